// Round 5
// baseline (300.178 us; speedup 1.0000x reference)
//
#include <hip/hip_runtime.h>

typedef unsigned short u16;
typedef unsigned int   u32;
typedef __attribute__((ext_vector_type(8))) short short8;
typedef __attribute__((ext_vector_type(4))) unsigned int u32x4;
typedef __attribute__((ext_vector_type(4))) float f32x4;

__device__ __forceinline__ u16 f2b(float f) {
    u32 u = __float_as_uint(f);
    u32 r = (u + 0x7fffu + ((u >> 16) & 1u)) >> 16;   // round-to-nearest-even
    return (u16)r;
}
__device__ __forceinline__ float blo(u32 w) { return __uint_as_float(w << 16); }
__device__ __forceinline__ float bhi(u32 w) { return __uint_as_float(w & 0xffff0000u); }

// ---------------- prep weights (transpose+bf16) AND edge histogram, one launch ----------------
__global__ void k_ph(const float* __restrict__ W0, const float* __restrict__ W1,
                     const float* __restrict__ W2, const float* __restrict__ W3,
                     const float* __restrict__ W4, u16* __restrict__ Wt,
                     const int* __restrict__ dst, int* __restrict__ cnt, int E) {
    int b = blockIdx.x, t = threadIdx.x;
    if (b < 320) {
        int id = b * 256 + t;
        if (id < 5 * 16384) {
            int g = id >> 14, j = (id >> 7) & 127, k = id & 127;
            const float* W = g == 0 ? W0 : g == 1 ? W1 : g == 2 ? W2 : g == 3 ? W3 : W4;
            Wt[id] = f2b(W[k * 128 + j]);
        }
    } else {
        int e = (b - 320) * 256 + t;
        if (e < E) atomicAdd(&cnt[dst[e]], 1);
    }
}

// ---------------- fused 5-GEMM: A-tile in LDS (17.4KB), B read direct from L2 ----------------
// H/K/V interleaved into HKV[n][3][128]; Q pre-scaled by 1/sqrt(128); a_s/a_d in g==0 epilogue.
__global__ __launch_bounds__(256) void k_gemm(const float* __restrict__ X, const u16* __restrict__ Wt,
                                              u16* __restrict__ HKV, u16* __restrict__ Q, u16* __restrict__ R,
                                              const float* __restrict__ asrc, const float* __restrict__ adst,
                                              float* __restrict__ a_s, float* __restrict__ a_d, int N) {
    __shared__ u16 As[64][136];   // 17.4 KB
    const int tid = threadIdx.x;
    const int row0 = blockIdx.x * 64;

    // stage A (fp32 -> bf16)
    for (int c = tid; c < 64 * 16; c += 256) {
        int r = c >> 4, col8 = (c & 15) * 8;
        int grow = row0 + r;
        short8 vv = {0, 0, 0, 0, 0, 0, 0, 0};
        if (grow < N) {
            const float* xp = X + (size_t)grow * 128 + col8;
            float4 f0 = *reinterpret_cast<const float4*>(xp);
            float4 f1 = *reinterpret_cast<const float4*>(xp + 4);
            vv[0] = (short)f2b(f0.x); vv[1] = (short)f2b(f0.y);
            vv[2] = (short)f2b(f0.z); vv[3] = (short)f2b(f0.w);
            vv[4] = (short)f2b(f1.x); vv[5] = (short)f2b(f1.y);
            vv[6] = (short)f2b(f1.z); vv[7] = (short)f2b(f1.w);
        }
        *reinterpret_cast<short8*>(&As[r][col8]) = vv;
    }
    __syncthreads();

    const int wid = tid >> 6, lane = tid & 63;
    const int l15 = lane & 15;
    const int arow = wid * 16 + l15;
    const int kg = (lane >> 4) * 8;

    short8 af[4];
#pragma unroll
    for (int kc = 0; kc < 4; kc++)
        af[kc] = *reinterpret_cast<const short8*>(&As[arow][kc * 32 + kg]);

    const int rbase = row0 + wid * 16 + ((lane >> 4) << 2);
    const float isd = 0.08838834764831845f;   // 1/sqrt(128)

    for (int g = 0; g < 5; g++) {
        const u16* wt = Wt + g * 16384;
        u16* outp;
        int stride;
        float osc;
        if (g == 0)      { outp = HKV;       stride = 384; osc = 1.f; }
        else if (g == 1) { outp = Q;         stride = 128; osc = isd; }
        else if (g == 2) { outp = HKV + 128; stride = 384; osc = 1.f; }
        else if (g == 3) { outp = HKV + 256; stride = 384; osc = 1.f; }
        else             { outp = R;         stride = 128; osc = 1.f; }

        float ps[4] = {0.f, 0.f, 0.f, 0.f};
        float pd[4] = {0.f, 0.f, 0.f, 0.f};

#pragma unroll
        for (int c = 0; c < 8; c++) {
            const int bcol = c * 16 + l15;
            const u16* bptr = wt + bcol * 128 + kg;
            f32x4 acc = {0.f, 0.f, 0.f, 0.f};
#pragma unroll
            for (int kc = 0; kc < 4; kc++) {
                short8 bf = *reinterpret_cast<const short8*>(bptr + kc * 32);
                acc = __builtin_amdgcn_mfma_f32_16x16x32_bf16(af[kc], bf, acc, 0, 0, 0);
            }
#pragma unroll
            for (int r = 0; r < 4; r++) {
                int grow = rbase + r;
                if (grow < N) outp[(size_t)grow * stride + bcol] = f2b(acc[r] * osc);
            }
            if (g == 0) {
                float vs = asrc[bcol], vd = adst[bcol];
#pragma unroll
                for (int r = 0; r < 4; r++) {
                    ps[r] += acc[r] * vs;
                    pd[r] += acc[r] * vd;
                }
            }
        }
        if (g == 0) {
#pragma unroll
            for (int off = 1; off < 16; off <<= 1) {
#pragma unroll
                for (int r = 0; r < 4; r++) {
                    ps[r] += __shfl_xor(ps[r], off);
                    pd[r] += __shfl_xor(pd[r], off);
                }
            }
            if (l15 == 0) {
#pragma unroll
                for (int r = 0; r < 4; r++) {
                    int grow = rbase + r;
                    if (grow < N) { a_s[grow] = ps[r]; a_d[grow] = pd[r]; }
                }
            }
        }
    }
}

// ---------------- CSR scan chain ----------------
__global__ __launch_bounds__(256) void k_scan1(const int* __restrict__ cnt, int* __restrict__ excl,
                                               int* __restrict__ bsum, int N) {
    __shared__ int sh[256];
    int t = threadIdx.x;
    int base = blockIdx.x * 1024 + t * 4;
    int v[4], s = 0;
#pragma unroll
    for (int j = 0; j < 4; j++) {
        int i = base + j;
        v[j] = (i < N) ? cnt[i] : 0;
        s += v[j];
    }
    sh[t] = s;
    __syncthreads();
    for (int off = 1; off < 256; off <<= 1) {
        int x = (t >= off) ? sh[t - off] : 0;
        __syncthreads();
        sh[t] += x;
        __syncthreads();
    }
    int run = sh[t] - s;
#pragma unroll
    for (int j = 0; j < 4; j++) {
        int i = base + j;
        if (i < N) excl[i] = run;
        run += v[j];
    }
    if (t == 255) bsum[blockIdx.x] = sh[255];
}

__global__ __launch_bounds__(256) void k_scan2(const int* __restrict__ bsum, int* __restrict__ boff,
                                               int nb, int* __restrict__ rp_last) {
    __shared__ int sh[256];
    int t = threadIdx.x;
    int v = (t < nb) ? bsum[t] : 0;
    sh[t] = v;
    __syncthreads();
    for (int off = 1; off < 256; off <<= 1) {
        int x = (t >= off) ? sh[t - off] : 0;
        __syncthreads();
        sh[t] += x;
        __syncthreads();
    }
    if (t < nb) boff[t] = sh[t] - v;
    if (t == 255) *rp_last = sh[255];
}

__global__ void k_scan3(int* __restrict__ rp, const int* __restrict__ boff, int* __restrict__ next, int N) {
    int i = blockIdx.x * 256 + threadIdx.x;
    if (i < N) {
        int v = rp[i] + boff[i >> 10];
        rp[i] = v;
        next[i] = v;
    }
}

// ---------------- fill: CSR scatter + precompute GAT weight per edge ----------------
// es[p] = { src*384 (HKV row byte-elem offset), bits(exp(leakyrelu(a_s[src]+a_d[dst]))) }
__global__ void k_fill(const int* __restrict__ src, const int* __restrict__ dst, int* __restrict__ next,
                       const float* __restrict__ a_s, const float* __restrict__ a_d,
                       int2* __restrict__ es, int E) {
    int e = blockIdx.x * 256 + threadIdx.x;
    if (e < E) {
        int s = src[e], d = dst[e];
        float gl = a_s[s] + a_d[d];
        gl = gl >= 0.f ? gl : 0.2f * gl;      // LeakyReLU(0.2)
        float wg = __expf(gl);
        int p = atomicAdd(&next[d], 1);
        int2 v;
        v.x = s * 384;
        v.y = __float_as_int(wg);
        es[p] = v;
    }
}

// ---------------- fused edge phase ----------------
// Wave per node; 4 edges concurrently via 16-lane groups; lane holds 8 dims (dwordx4).
// No max-subtraction (logits bounded; softmax shift-invariant; validated r1-r4).
__global__ __launch_bounds__(256) void k_edge(const int* __restrict__ rp, const int2* __restrict__ es,
                                              const u16* __restrict__ HKV, const u16* __restrict__ Q,
                                              const u16* __restrict__ R, const float* __restrict__ bias,
                                              float* __restrict__ out, int N) {
    const int wid = threadIdx.x >> 6, lane = threadIdx.x & 63;
    const int n = blockIdx.x * 4 + wid;
    if (n >= N) return;
    const int l = lane & 15, g = lane >> 4;
    const int l8 = l * 8;

    u32x4 qv = *reinterpret_cast<const u32x4*>(Q + (size_t)n * 128 + l8);
    float qf[8];
#pragma unroll
    for (int i = 0; i < 4; i++) { qf[2 * i] = blo(qv[i]); qf[2 * i + 1] = bhi(qv[i]); }
    const int beg = rp[n], end = rp[n + 1];

    float ag[8] = {0.f, 0.f, 0.f, 0.f, 0.f, 0.f, 0.f, 0.f};
    float at[8] = {0.f, 0.f, 0.f, 0.f, 0.f, 0.f, 0.f, 0.f};
    float zg = 0.f, zt = 0.f;

    int p = beg;
    // full double-quads: no masking, 6 gathers in flight
    for (; p + 8 <= end; p += 8) {
        int2 e0 = es[p + g];
        int2 e1 = es[p + 4 + g];
        const u16* b0 = HKV + e0.x;
        const u16* b1 = HKV + e1.x;
        u32x4 k0 = *reinterpret_cast<const u32x4*>(b0 + 128 + l8);
        u32x4 k1 = *reinterpret_cast<const u32x4*>(b1 + 128 + l8);
        u32x4 h0 = *reinterpret_cast<const u32x4*>(b0 + l8);
        u32x4 h1 = *reinterpret_cast<const u32x4*>(b1 + l8);
        u32x4 v0 = *reinterpret_cast<const u32x4*>(b0 + 256 + l8);
        u32x4 v1 = *reinterpret_cast<const u32x4*>(b1 + 256 + l8);
        float wg0 = __int_as_float(e0.y), wg1 = __int_as_float(e1.y);

        float d0 = 0.f, d1 = 0.f;
#pragma unroll
        for (int i = 0; i < 4; i++) {
            d0 = fmaf(qf[2 * i], blo(k0[i]), d0);
            d0 = fmaf(qf[2 * i + 1], bhi(k0[i]), d0);
            d1 = fmaf(qf[2 * i], blo(k1[i]), d1);
            d1 = fmaf(qf[2 * i + 1], bhi(k1[i]), d1);
        }
#pragma unroll
        for (int off = 1; off < 16; off <<= 1) {
            d0 += __shfl_xor(d0, off);
            d1 += __shfl_xor(d1, off);
        }
        float wt0 = __expf(d0), wt1 = __expf(d1);

#pragma unroll
        for (int i = 0; i < 4; i++) {
            ag[2 * i]     = fmaf(wg0, blo(h0[i]), ag[2 * i]);
            ag[2 * i + 1] = fmaf(wg0, bhi(h0[i]), ag[2 * i + 1]);
            ag[2 * i]     = fmaf(wg1, blo(h1[i]), ag[2 * i]);
            ag[2 * i + 1] = fmaf(wg1, bhi(h1[i]), ag[2 * i + 1]);
            at[2 * i]     = fmaf(wt0, blo(v0[i]), at[2 * i]);
            at[2 * i + 1] = fmaf(wt0, bhi(v0[i]), at[2 * i + 1]);
            at[2 * i]     = fmaf(wt1, blo(v1[i]), at[2 * i]);
            at[2 * i + 1] = fmaf(wt1, bhi(v1[i]), at[2 * i + 1]);
        }
        zg += wg0 + wg1;
        zt += wt0 + wt1;
    }
    // remainder (masked quads)
    for (; p < end; p += 4) {
        int pe = p + g;
        if (pe < end) {
            int2 e0 = es[pe];
            const u16* b0 = HKV + e0.x;
            u32x4 k0 = *reinterpret_cast<const u32x4*>(b0 + 128 + l8);
            u32x4 h0 = *reinterpret_cast<const u32x4*>(b0 + l8);
            u32x4 v0 = *reinterpret_cast<const u32x4*>(b0 + 256 + l8);
            float wg0 = __int_as_float(e0.y);
            float d0 = 0.f;
#pragma unroll
            for (int i = 0; i < 4; i++) {
                d0 = fmaf(qf[2 * i], blo(k0[i]), d0);
                d0 = fmaf(qf[2 * i + 1], bhi(k0[i]), d0);
            }
#pragma unroll
            for (int off = 1; off < 16; off <<= 1) d0 += __shfl_xor(d0, off);
            float wt0 = __expf(d0);
#pragma unroll
            for (int i = 0; i < 4; i++) {
                ag[2 * i]     = fmaf(wg0, blo(h0[i]), ag[2 * i]);
                ag[2 * i + 1] = fmaf(wg0, bhi(h0[i]), ag[2 * i + 1]);
                at[2 * i]     = fmaf(wt0, blo(v0[i]), at[2 * i]);
                at[2 * i + 1] = fmaf(wt0, bhi(v0[i]), at[2 * i + 1]);
            }
            zg += wg0;
            zt += wt0;
        }
    }

    // cross-group reduce
#pragma unroll
    for (int j = 0; j < 8; j++) {
        ag[j] += __shfl_xor(ag[j], 16); ag[j] += __shfl_xor(ag[j], 32);
        at[j] += __shfl_xor(at[j], 16); at[j] += __shfl_xor(at[j], 32);
    }
    zg += __shfl_xor(zg, 16); zg += __shfl_xor(zg, 32);
    zt += __shfl_xor(zt, 16); zt += __shfl_xor(zt, 32);

    float ig = 1.f / (zg + 1e-16f), it = 1.f / (zt + 1e-16f);
    u32x4 rv = *reinterpret_cast<const u32x4*>(R + (size_t)n * 128 + l8);
    float4 b0 = *reinterpret_cast<const float4*>(bias + l8);
    float4 b1 = *reinterpret_cast<const float4*>(bias + l8 + 4);
    float bb[8] = {b0.x, b0.y, b0.z, b0.w, b1.x, b1.y, b1.z, b1.w};

    float o[8];
    float ss = 0.f;
#pragma unroll
    for (int i = 0; i < 4; i++) {
        float r0 = blo(rv[i]), r1 = bhi(rv[i]);
        float g0 = fmaxf(ag[2 * i] * ig + bb[2 * i], 0.f);
        float g1 = fmaxf(ag[2 * i + 1] * ig + bb[2 * i + 1], 0.f);
        o[2 * i] = g0 + at[2 * i] * it + r0;
        o[2 * i + 1] = g1 + at[2 * i + 1] * it + r1;
        ss += o[2 * i] * o[2 * i] + o[2 * i + 1] * o[2 * i + 1];
    }
#pragma unroll
    for (int off = 1; off < 16; off <<= 1) ss += __shfl_xor(ss, off);
    float inv = 1.f / fmaxf(sqrtf(ss), 1e-12f);

    if (g == 0) {
        float4 s0 = {o[0] * inv, o[1] * inv, o[2] * inv, o[3] * inv};
        float4 s1 = {o[4] * inv, o[5] * inv, o[6] * inv, o[7] * inv};
        float* op = out + (size_t)n * 128 + l8;
        *reinterpret_cast<float4*>(op) = s0;
        *reinterpret_cast<float4*>(op + 4) = s1;
    }
}

// ---------------- host launcher ----------------
extern "C" void kernel_launch(void* const* d_in, const int* in_sizes, int n_in,
                              void* d_out, int out_size, void* d_ws, size_t ws_size,
                              hipStream_t stream) {
    const int* edge = (const int*)d_in[1];
    const float* emb = (const float*)d_in[2];
    const float* gat_W = (const float*)d_in[3];
    const float* a_src = (const float*)d_in[4];
    const float* a_dst = (const float*)d_in[5];
    const float* bias = (const float*)d_in[6];
    const float* Wq = (const float*)d_in[7];
    const float* Wk = (const float*)d_in[8];
    const float* Wv = (const float*)d_in[9];
    const float* Wr = (const float*)d_in[10];

    const int E = in_sizes[1] / 2;
    const int N = in_sizes[2] / 128;
    const int* src = edge;
    const int* dst = edge + E;
    float* out = (float*)d_out;

    char* w = (char*)d_ws;
    auto alloc = [&](size_t bytes) -> char* {
        char* p = w;
        w += (bytes + 255) & ~(size_t)255;
        return p;
    };
    u16* HKV = (u16*)alloc((size_t)N * 384 * 2);    // [n][H|K|V][128]
    u16* Q   = (u16*)alloc((size_t)N * 128 * 2);
    u16* R   = (u16*)alloc((size_t)N * 128 * 2);
    u16* Wt  = (u16*)alloc(5 * 128 * 128 * 2);
    float* a_s = (float*)alloc((size_t)N * 4);
    float* a_d = (float*)alloc((size_t)N * 4);
    int* cnt  = (int*)alloc((size_t)N * 4);
    int* rp   = (int*)alloc((size_t)(N + 1) * 4);
    int* nxt  = (int*)alloc((size_t)N * 4);
    int* bsum = (int*)alloc(1024);
    int* boff = (int*)alloc(1024);
    int2* es  = (int2*)alloc((size_t)E * 8);

    const int nb = (N + 1023) / 1024;
    const int nhist = (E + 255) / 256;

    hipMemsetAsync(cnt, 0, (size_t)N * 4, stream);
    k_ph<<<320 + nhist, 256, 0, stream>>>(gat_W, Wq, Wk, Wv, Wr, Wt, dst, cnt, E);
    k_gemm<<<(N + 63) / 64, 256, 0, stream>>>(emb, Wt, HKV, Q, R, a_src, a_dst, a_s, a_d, N);
    k_scan1<<<nb, 256, 0, stream>>>(cnt, rp, bsum, N);
    k_scan2<<<1, 256, 0, stream>>>(bsum, boff, nb, rp + N);
    k_scan3<<<(N + 255) / 256, 256, 0, stream>>>(rp, boff, nxt, N);
    k_fill<<<nhist, 256, 0, stream>>>(src, dst, nxt, a_s, a_d, es, E);
    k_edge<<<(N + 3) / 4, 256, 0, stream>>>(rp, es, HKV, Q, R, bias, out, N);
}

// Round 6
// 219.854 us; speedup vs baseline: 1.3654x; 1.3654x over previous
//
#include <hip/hip_runtime.h>

typedef unsigned short u16;
typedef unsigned int   u32;
typedef __attribute__((ext_vector_type(8))) short short8;
typedef __attribute__((ext_vector_type(4))) unsigned int u32x4;
typedef __attribute__((ext_vector_type(4))) float f32x4;

__device__ __forceinline__ u16 f2b(float f) {
    u32 u = __float_as_uint(f);
    u32 r = (u + 0x7fffu + ((u >> 16) & 1u)) >> 16;   // round-to-nearest-even
    return (u16)r;
}
__device__ __forceinline__ float blo(u32 w) { return __uint_as_float(w << 16); }
__device__ __forceinline__ float bhi(u32 w) { return __uint_as_float(w & 0xffff0000u); }

// ---------------- prep: X->bf16 convert, weight transpose+bf16, edge histogram ----------------
// blocks [0, nxc): Xb convert; [nxc, nxc+320): Wt; [nxc+320, ...): histogram
__global__ void k_ph(const float* __restrict__ X, u16* __restrict__ Xb, int NX,
                     const float* __restrict__ W0, const float* __restrict__ W1,
                     const float* __restrict__ W2, const float* __restrict__ W3,
                     const float* __restrict__ W4, u16* __restrict__ Wt,
                     const int* __restrict__ dst, int* __restrict__ cnt, int E, int nxc) {
    int b = blockIdx.x, t = threadIdx.x;
    if (b < nxc) {
        int i0 = b * 2048 + t * 8;
        if (i0 + 8 <= NX) {
            float4 f0 = *reinterpret_cast<const float4*>(X + i0);
            float4 f1 = *reinterpret_cast<const float4*>(X + i0 + 4);
            short8 vv;
            vv[0] = (short)f2b(f0.x); vv[1] = (short)f2b(f0.y);
            vv[2] = (short)f2b(f0.z); vv[3] = (short)f2b(f0.w);
            vv[4] = (short)f2b(f1.x); vv[5] = (short)f2b(f1.y);
            vv[6] = (short)f2b(f1.z); vv[7] = (short)f2b(f1.w);
            *reinterpret_cast<short8*>(Xb + i0) = vv;
        }
    } else if (b < nxc + 320) {
        int id = (b - nxc) * 256 + t;
        if (id < 5 * 16384) {
            int g = id >> 14, j = (id >> 7) & 127, k = id & 127;
            const float* W = g == 0 ? W0 : g == 1 ? W1 : g == 2 ? W2 : g == 3 ? W3 : W4;
            Wt[id] = f2b(W[k * 128 + j]);
        }
    } else {
        int e = (b - nxc - 320) * 256 + t;
        if (e < E) atomicAdd(&cnt[dst[e]], 1);
    }
}

// ---------------- GEMM: grid (ceil(N/128), 5), 512 threads, A+B in LDS (69.6KB) ----------------
// g = blockIdx.y selects weight matrix. H/K/V interleaved HKV[n][3][128]; Q pre-scaled 1/sqrt(128).
// g==0 blocks also compute a_s/a_d.
__global__ __launch_bounds__(512) void k_gemm(const u16* __restrict__ Xb, const u16* __restrict__ Wt,
                                              u16* __restrict__ HKV, u16* __restrict__ Q, u16* __restrict__ R,
                                              const float* __restrict__ asrc, const float* __restrict__ adst,
                                              float* __restrict__ a_s, float* __restrict__ a_d, int N) {
    __shared__ u16 As[128][136];   // 34.8 KB
    __shared__ u16 Bs[128][136];   // 34.8 KB
    const int tid = threadIdx.x;
    const int g = blockIdx.y;
    const int row0 = blockIdx.x * 128;
    const u16* wt = Wt + g * 16384;

    // stage A (bf16, vectorized) + B
    for (int c = tid; c < 128 * 16; c += 512) {
        int r = c >> 4, col8 = (c & 15) * 8;
        int grow = row0 + r;
        short8 av = {0, 0, 0, 0, 0, 0, 0, 0};
        if (grow < N) av = *reinterpret_cast<const short8*>(Xb + (size_t)grow * 128 + col8);
        *reinterpret_cast<short8*>(&As[r][col8]) = av;
        *reinterpret_cast<short8*>(&Bs[r][col8]) =
            *reinterpret_cast<const short8*>(wt + r * 128 + col8);
    }
    __syncthreads();

    const int wid = tid >> 6, lane = tid & 63;
    const int l15 = lane & 15;
    const int arow = wid * 16 + l15;
    const int kg = (lane >> 4) * 8;

    short8 af[4];
#pragma unroll
    for (int kc = 0; kc < 4; kc++)
        af[kc] = *reinterpret_cast<const short8*>(&As[arow][kc * 32 + kg]);

    const int rbase = row0 + wid * 16 + ((lane >> 4) << 2);
    const float isd = 0.08838834764831845f;   // 1/sqrt(128)

    u16* outp;
    int stride;
    float osc = 1.f;
    if (g == 0)      { outp = HKV;       stride = 384; }
    else if (g == 1) { outp = Q;         stride = 128; osc = isd; }
    else if (g == 2) { outp = HKV + 128; stride = 384; }
    else if (g == 3) { outp = HKV + 256; stride = 384; }
    else             { outp = R;         stride = 128; }

    float ps[4] = {0.f, 0.f, 0.f, 0.f};
    float pd[4] = {0.f, 0.f, 0.f, 0.f};

#pragma unroll
    for (int c = 0; c < 8; c++) {
        const int bcol = c * 16 + l15;
        f32x4 acc = {0.f, 0.f, 0.f, 0.f};
#pragma unroll
        for (int kc = 0; kc < 4; kc++) {
            short8 bf = *reinterpret_cast<const short8*>(&Bs[bcol][kc * 32 + kg]);
            acc = __builtin_amdgcn_mfma_f32_16x16x32_bf16(af[kc], bf, acc, 0, 0, 0);
        }
#pragma unroll
        for (int r = 0; r < 4; r++) {
            int grow = rbase + r;
            if (grow < N) outp[(size_t)grow * stride + bcol] = f2b(acc[r] * osc);
        }
        if (g == 0) {
            float vs = asrc[bcol], vd = adst[bcol];
#pragma unroll
            for (int r = 0; r < 4; r++) {
                ps[r] += acc[r] * vs;
                pd[r] += acc[r] * vd;
            }
        }
    }
    if (g == 0) {
#pragma unroll
        for (int off = 1; off < 16; off <<= 1) {
#pragma unroll
            for (int r = 0; r < 4; r++) {
                ps[r] += __shfl_xor(ps[r], off);
                pd[r] += __shfl_xor(pd[r], off);
            }
        }
        if (l15 == 0) {
#pragma unroll
            for (int r = 0; r < 4; r++) {
                int grow = rbase + r;
                if (grow < N) { a_s[grow] = ps[r]; a_d[grow] = pd[r]; }
            }
        }
    }
}

// ---------------- CSR scan chain ----------------
__global__ __launch_bounds__(256) void k_scan1(const int* __restrict__ cnt, int* __restrict__ excl,
                                               int* __restrict__ bsum, int N) {
    __shared__ int sh[256];
    int t = threadIdx.x;
    int base = blockIdx.x * 1024 + t * 4;
    int v[4], s = 0;
#pragma unroll
    for (int j = 0; j < 4; j++) {
        int i = base + j;
        v[j] = (i < N) ? cnt[i] : 0;
        s += v[j];
    }
    sh[t] = s;
    __syncthreads();
    for (int off = 1; off < 256; off <<= 1) {
        int x = (t >= off) ? sh[t - off] : 0;
        __syncthreads();
        sh[t] += x;
        __syncthreads();
    }
    int run = sh[t] - s;
#pragma unroll
    for (int j = 0; j < 4; j++) {
        int i = base + j;
        if (i < N) excl[i] = run;
        run += v[j];
    }
    if (t == 255) bsum[blockIdx.x] = sh[255];
}

__global__ __launch_bounds__(256) void k_scan2(const int* __restrict__ bsum, int* __restrict__ boff,
                                               int nb, int* __restrict__ rp_last) {
    __shared__ int sh[256];
    int t = threadIdx.x;
    int v = (t < nb) ? bsum[t] : 0;
    sh[t] = v;
    __syncthreads();
    for (int off = 1; off < 256; off <<= 1) {
        int x = (t >= off) ? sh[t - off] : 0;
        __syncthreads();
        sh[t] += x;
        __syncthreads();
    }
    if (t < nb) boff[t] = sh[t] - v;
    if (t == 255) *rp_last = sh[255];
}

__global__ void k_scan3(int* __restrict__ rp, const int* __restrict__ boff, int* __restrict__ next, int N) {
    int i = blockIdx.x * 256 + threadIdx.x;
    if (i < N) {
        int v = rp[i] + boff[i >> 10];
        rp[i] = v;
        next[i] = v;
    }
}

// ---------------- fill: CSR scatter + precompute GAT weight per edge ----------------
__global__ void k_fill(const int* __restrict__ src, const int* __restrict__ dst, int* __restrict__ next,
                       const float* __restrict__ a_s, const float* __restrict__ a_d,
                       int2* __restrict__ es, int E) {
    int e = blockIdx.x * 256 + threadIdx.x;
    if (e < E) {
        int s = src[e], d = dst[e];
        float gl = a_s[s] + a_d[d];
        gl = gl >= 0.f ? gl : 0.2f * gl;      // LeakyReLU(0.2)
        float wg = __expf(gl);
        int p = atomicAdd(&next[d], 1);
        int2 v;
        v.x = s * 384;
        v.y = __float_as_int(wg);
        es[p] = v;
    }
}

// ---------------- fused edge phase ----------------
__global__ __launch_bounds__(256) void k_edge(const int* __restrict__ rp, const int2* __restrict__ es,
                                              const u16* __restrict__ HKV, const u16* __restrict__ Q,
                                              const u16* __restrict__ R, const float* __restrict__ bias,
                                              float* __restrict__ out, int N) {
    const int wid = threadIdx.x >> 6, lane = threadIdx.x & 63;
    const int n = blockIdx.x * 4 + wid;
    if (n >= N) return;
    const int l = lane & 15, g = lane >> 4;
    const int l8 = l * 8;

    u32x4 qv = *reinterpret_cast<const u32x4*>(Q + (size_t)n * 128 + l8);
    float qf[8];
#pragma unroll
    for (int i = 0; i < 4; i++) { qf[2 * i] = blo(qv[i]); qf[2 * i + 1] = bhi(qv[i]); }
    const int beg = rp[n], end = rp[n + 1];

    float ag[8] = {0.f, 0.f, 0.f, 0.f, 0.f, 0.f, 0.f, 0.f};
    float at[8] = {0.f, 0.f, 0.f, 0.f, 0.f, 0.f, 0.f, 0.f};
    float zg = 0.f, zt = 0.f;

    int p = beg;
    for (; p + 8 <= end; p += 8) {
        int2 e0 = es[p + g];
        int2 e1 = es[p + 4 + g];
        const u16* b0 = HKV + e0.x;
        const u16* b1 = HKV + e1.x;
        u32x4 k0 = *reinterpret_cast<const u32x4*>(b0 + 128 + l8);
        u32x4 k1 = *reinterpret_cast<const u32x4*>(b1 + 128 + l8);
        u32x4 h0 = *reinterpret_cast<const u32x4*>(b0 + l8);
        u32x4 h1 = *reinterpret_cast<const u32x4*>(b1 + l8);
        u32x4 v0 = *reinterpret_cast<const u32x4*>(b0 + 256 + l8);
        u32x4 v1 = *reinterpret_cast<const u32x4*>(b1 + 256 + l8);
        float wg0 = __int_as_float(e0.y), wg1 = __int_as_float(e1.y);

        float d0 = 0.f, d1 = 0.f;
#pragma unroll
        for (int i = 0; i < 4; i++) {
            d0 = fmaf(qf[2 * i], blo(k0[i]), d0);
            d0 = fmaf(qf[2 * i + 1], bhi(k0[i]), d0);
            d1 = fmaf(qf[2 * i], blo(k1[i]), d1);
            d1 = fmaf(qf[2 * i + 1], bhi(k1[i]), d1);
        }
#pragma unroll
        for (int off = 1; off < 16; off <<= 1) {
            d0 += __shfl_xor(d0, off);
            d1 += __shfl_xor(d1, off);
        }
        float wt0 = __expf(d0), wt1 = __expf(d1);

#pragma unroll
        for (int i = 0; i < 4; i++) {
            ag[2 * i]     = fmaf(wg0, blo(h0[i]), ag[2 * i]);
            ag[2 * i + 1] = fmaf(wg0, bhi(h0[i]), ag[2 * i + 1]);
            ag[2 * i]     = fmaf(wg1, blo(h1[i]), ag[2 * i]);
            ag[2 * i + 1] = fmaf(wg1, bhi(h1[i]), ag[2 * i + 1]);
            at[2 * i]     = fmaf(wt0, blo(v0[i]), at[2 * i]);
            at[2 * i + 1] = fmaf(wt0, bhi(v0[i]), at[2 * i + 1]);
            at[2 * i]     = fmaf(wt1, blo(v1[i]), at[2 * i]);
            at[2 * i + 1] = fmaf(wt1, bhi(v1[i]), at[2 * i + 1]);
        }
        zg += wg0 + wg1;
        zt += wt0 + wt1;
    }
    for (; p < end; p += 4) {
        int pe = p + g;
        if (pe < end) {
            int2 e0 = es[pe];
            const u16* b0 = HKV + e0.x;
            u32x4 k0 = *reinterpret_cast<const u32x4*>(b0 + 128 + l8);
            u32x4 h0 = *reinterpret_cast<const u32x4*>(b0 + l8);
            u32x4 v0 = *reinterpret_cast<const u32x4*>(b0 + 256 + l8);
            float wg0 = __int_as_float(e0.y);
            float d0 = 0.f;
#pragma unroll
            for (int i = 0; i < 4; i++) {
                d0 = fmaf(qf[2 * i], blo(k0[i]), d0);
                d0 = fmaf(qf[2 * i + 1], bhi(k0[i]), d0);
            }
#pragma unroll
            for (int off = 1; off < 16; off <<= 1) d0 += __shfl_xor(d0, off);
            float wt0 = __expf(d0);
#pragma unroll
            for (int i = 0; i < 4; i++) {
                ag[2 * i]     = fmaf(wg0, blo(h0[i]), ag[2 * i]);
                ag[2 * i + 1] = fmaf(wg0, bhi(h0[i]), ag[2 * i + 1]);
                at[2 * i]     = fmaf(wt0, blo(v0[i]), at[2 * i]);
                at[2 * i + 1] = fmaf(wt0, bhi(v0[i]), at[2 * i + 1]);
            }
            zg += wg0;
            zt += wt0;
        }
    }

    // cross-group reduce
#pragma unroll
    for (int j = 0; j < 8; j++) {
        ag[j] += __shfl_xor(ag[j], 16); ag[j] += __shfl_xor(ag[j], 32);
        at[j] += __shfl_xor(at[j], 16); at[j] += __shfl_xor(at[j], 32);
    }
    zg += __shfl_xor(zg, 16); zg += __shfl_xor(zg, 32);
    zt += __shfl_xor(zt, 16); zt += __shfl_xor(zt, 32);

    float ig = 1.f / (zg + 1e-16f), it = 1.f / (zt + 1e-16f);
    u32x4 rv = *reinterpret_cast<const u32x4*>(R + (size_t)n * 128 + l8);
    float4 b0 = *reinterpret_cast<const float4*>(bias + l8);
    float4 b1 = *reinterpret_cast<const float4*>(bias + l8 + 4);
    float bb[8] = {b0.x, b0.y, b0.z, b0.w, b1.x, b1.y, b1.z, b1.w};

    float o[8];
    float ss = 0.f;
#pragma unroll
    for (int i = 0; i < 4; i++) {
        float r0 = blo(rv[i]), r1 = bhi(rv[i]);
        float g0 = fmaxf(ag[2 * i] * ig + bb[2 * i], 0.f);
        float g1 = fmaxf(ag[2 * i + 1] * ig + bb[2 * i + 1], 0.f);
        o[2 * i] = g0 + at[2 * i] * it + r0;
        o[2 * i + 1] = g1 + at[2 * i + 1] * it + r1;
        ss += o[2 * i] * o[2 * i] + o[2 * i + 1] * o[2 * i + 1];
    }
#pragma unroll
    for (int off = 1; off < 16; off <<= 1) ss += __shfl_xor(ss, off);
    float inv = 1.f / fmaxf(sqrtf(ss), 1e-12f);

    if (g == 0) {
        float4 s0 = {o[0] * inv, o[1] * inv, o[2] * inv, o[3] * inv};
        float4 s1 = {o[4] * inv, o[5] * inv, o[6] * inv, o[7] * inv};
        float* op = out + (size_t)n * 128 + l8;
        *reinterpret_cast<float4*>(op) = s0;
        *reinterpret_cast<float4*>(op + 4) = s1;
    }
}

// ---------------- host launcher ----------------
extern "C" void kernel_launch(void* const* d_in, const int* in_sizes, int n_in,
                              void* d_out, int out_size, void* d_ws, size_t ws_size,
                              hipStream_t stream) {
    const int* edge = (const int*)d_in[1];
    const float* emb = (const float*)d_in[2];
    const float* gat_W = (const float*)d_in[3];
    const float* a_src = (const float*)d_in[4];
    const float* a_dst = (const float*)d_in[5];
    const float* bias = (const float*)d_in[6];
    const float* Wq = (const float*)d_in[7];
    const float* Wk = (const float*)d_in[8];
    const float* Wv = (const float*)d_in[9];
    const float* Wr = (const float*)d_in[10];

    const int E = in_sizes[1] / 2;
    const int N = in_sizes[2] / 128;
    const int* src = edge;
    const int* dst = edge + E;
    float* out = (float*)d_out;

    char* w = (char*)d_ws;
    auto alloc = [&](size_t bytes) -> char* {
        char* p = w;
        w += (bytes + 255) & ~(size_t)255;
        return p;
    };
    u16* HKV = (u16*)alloc((size_t)N * 384 * 2);    // [n][H|K|V][128]
    u16* Q   = (u16*)alloc((size_t)N * 128 * 2);
    u16* R   = (u16*)alloc((size_t)N * 128 * 2);
    u16* Xb  = (u16*)alloc((size_t)N * 128 * 2);
    u16* Wt  = (u16*)alloc(5 * 128 * 128 * 2);
    float* a_s = (float*)alloc((size_t)N * 4);
    float* a_d = (float*)alloc((size_t)N * 4);
    int* cnt  = (int*)alloc((size_t)N * 4);
    int* rp   = (int*)alloc((size_t)(N + 1) * 4);
    int* nxt  = (int*)alloc((size_t)N * 4);
    int* bsum = (int*)alloc(1024);
    int* boff = (int*)alloc(1024);
    int2* es  = (int2*)alloc((size_t)E * 8);

    const int NX = N * 128;
    const int nxc = (NX + 2047) / 2048;
    const int nb = (N + 1023) / 1024;
    const int nhist = (E + 255) / 256;

    hipMemsetAsync(cnt, 0, (size_t)N * 4, stream);
    k_ph<<<nxc + 320 + nhist, 256, 0, stream>>>(emb, Xb, NX, gat_W, Wq, Wk, Wv, Wr, Wt, dst, cnt, E, nxc);
    k_gemm<<<dim3((N + 127) / 128, 5), 512, 0, stream>>>(Xb, Wt, HKV, Q, R, a_src, a_dst, a_s, a_d, N);
    k_scan1<<<nb, 256, 0, stream>>>(cnt, rp, bsum, N);
    k_scan2<<<1, 256, 0, stream>>>(bsum, boff, nb, rp + N);
    k_scan3<<<(N + 255) / 256, 256, 0, stream>>>(rp, boff, nxt, N);
    k_fill<<<nhist, 256, 0, stream>>>(src, dst, nxt, a_s, a_d, es, E);
    k_edge<<<(N + 3) / 4, 256, 0, stream>>>(rp, es, HKV, Q, R, bias, out, N);
}

// Round 7
// 214.191 us; speedup vs baseline: 1.4015x; 1.0264x over previous
//
#include <hip/hip_runtime.h>

typedef unsigned short u16;
typedef unsigned int   u32;
typedef __attribute__((ext_vector_type(8))) short short8;
typedef __attribute__((ext_vector_type(4))) unsigned int u32x4;
typedef __attribute__((ext_vector_type(4))) float f32x4;

__device__ __forceinline__ u16 f2b(float f) {
    u32 u = __float_as_uint(f);
    u32 r = (u + 0x7fffu + ((u >> 16) & 1u)) >> 16;   // round-to-nearest-even
    return (u16)r;
}
__device__ __forceinline__ float blo(u32 w) { return __uint_as_float(w << 16); }
__device__ __forceinline__ float bhi(u32 w) { return __uint_as_float(w & 0xffff0000u); }

// ---------------- prep: X->bf16 convert, weight transpose+bf16, edge histogram ----------------
__global__ void k_ph(const float* __restrict__ X, u16* __restrict__ Xb, int NX,
                     const float* __restrict__ W0, const float* __restrict__ W1,
                     const float* __restrict__ W2, const float* __restrict__ W3,
                     const float* __restrict__ W4, u16* __restrict__ Wt,
                     const int* __restrict__ dst, int* __restrict__ cnt, int E, int nxc) {
    int b = blockIdx.x, t = threadIdx.x;
    if (b < nxc) {
        int i0 = b * 2048 + t * 8;
        if (i0 + 8 <= NX) {
            float4 f0 = *reinterpret_cast<const float4*>(X + i0);
            float4 f1 = *reinterpret_cast<const float4*>(X + i0 + 4);
            short8 vv;
            vv[0] = (short)f2b(f0.x); vv[1] = (short)f2b(f0.y);
            vv[2] = (short)f2b(f0.z); vv[3] = (short)f2b(f0.w);
            vv[4] = (short)f2b(f1.x); vv[5] = (short)f2b(f1.y);
            vv[6] = (short)f2b(f1.z); vv[7] = (short)f2b(f1.w);
            *reinterpret_cast<short8*>(Xb + i0) = vv;
        }
    } else if (b < nxc + 320) {
        int id = (b - nxc) * 256 + t;
        if (id < 5 * 16384) {
            int g = id >> 14, j = (id >> 7) & 127, k = id & 127;
            const float* W = g == 0 ? W0 : g == 1 ? W1 : g == 2 ? W2 : g == 3 ? W3 : W4;
            Wt[id] = f2b(W[k * 128 + j]);
        }
    } else {
        int e = (b - nxc - 320) * 256 + t;
        if (e < E) atomicAdd(&cnt[dst[e]], 1);
    }
}

// ---------------- GEMM: grid (ceil(N/128), 5), 512 threads, A+B in LDS (69.6KB) ----------------
__global__ __launch_bounds__(512) void k_gemm(const u16* __restrict__ Xb, const u16* __restrict__ Wt,
                                              u16* __restrict__ HKV, u16* __restrict__ Q, u16* __restrict__ R,
                                              const float* __restrict__ asrc, const float* __restrict__ adst,
                                              float* __restrict__ a_s, float* __restrict__ a_d, int N) {
    __shared__ u16 As[128][136];
    __shared__ u16 Bs[128][136];
    const int tid = threadIdx.x;
    const int g = blockIdx.y;
    const int row0 = blockIdx.x * 128;
    const u16* wt = Wt + g * 16384;

    for (int c = tid; c < 128 * 16; c += 512) {
        int r = c >> 4, col8 = (c & 15) * 8;
        int grow = row0 + r;
        short8 av = {0, 0, 0, 0, 0, 0, 0, 0};
        if (grow < N) av = *reinterpret_cast<const short8*>(Xb + (size_t)grow * 128 + col8);
        *reinterpret_cast<short8*>(&As[r][col8]) = av;
        *reinterpret_cast<short8*>(&Bs[r][col8]) =
            *reinterpret_cast<const short8*>(wt + r * 128 + col8);
    }
    __syncthreads();

    const int wid = tid >> 6, lane = tid & 63;
    const int l15 = lane & 15;
    const int arow = wid * 16 + l15;
    const int kg = (lane >> 4) * 8;

    short8 af[4];
#pragma unroll
    for (int kc = 0; kc < 4; kc++)
        af[kc] = *reinterpret_cast<const short8*>(&As[arow][kc * 32 + kg]);

    const int rbase = row0 + wid * 16 + ((lane >> 4) << 2);
    const float isd = 0.08838834764831845f;   // 1/sqrt(128)

    u16* outp;
    int stride;
    float osc = 1.f;
    if (g == 0)      { outp = HKV;       stride = 384; }
    else if (g == 1) { outp = Q;         stride = 128; osc = isd; }
    else if (g == 2) { outp = HKV + 128; stride = 384; }
    else if (g == 3) { outp = HKV + 256; stride = 384; }
    else             { outp = R;         stride = 128; }

    float ps[4] = {0.f, 0.f, 0.f, 0.f};
    float pd[4] = {0.f, 0.f, 0.f, 0.f};

#pragma unroll
    for (int c = 0; c < 8; c++) {
        const int bcol = c * 16 + l15;
        f32x4 acc = {0.f, 0.f, 0.f, 0.f};
#pragma unroll
        for (int kc = 0; kc < 4; kc++) {
            short8 bf = *reinterpret_cast<const short8*>(&Bs[bcol][kc * 32 + kg]);
            acc = __builtin_amdgcn_mfma_f32_16x16x32_bf16(af[kc], bf, acc, 0, 0, 0);
        }
#pragma unroll
        for (int r = 0; r < 4; r++) {
            int grow = rbase + r;
            if (grow < N) outp[(size_t)grow * stride + bcol] = f2b(acc[r] * osc);
        }
        if (g == 0) {
            float vs = asrc[bcol], vd = adst[bcol];
#pragma unroll
            for (int r = 0; r < 4; r++) {
                ps[r] += acc[r] * vs;
                pd[r] += acc[r] * vd;
            }
        }
    }
    if (g == 0) {
#pragma unroll
        for (int off = 1; off < 16; off <<= 1) {
#pragma unroll
            for (int r = 0; r < 4; r++) {
                ps[r] += __shfl_xor(ps[r], off);
                pd[r] += __shfl_xor(pd[r], off);
            }
        }
        if (l15 == 0) {
#pragma unroll
            for (int r = 0; r < 4; r++) {
                int grow = rbase + r;
                if (grow < N) { a_s[grow] = ps[r]; a_d[grow] = pd[r]; }
            }
        }
    }
}

// ---------------- CSR scan chain ----------------
__global__ __launch_bounds__(256) void k_scan1(const int* __restrict__ cnt, int* __restrict__ excl,
                                               int* __restrict__ bsum, int N) {
    __shared__ int sh[256];
    int t = threadIdx.x;
    int base = blockIdx.x * 1024 + t * 4;
    int v[4], s = 0;
#pragma unroll
    for (int j = 0; j < 4; j++) {
        int i = base + j;
        v[j] = (i < N) ? cnt[i] : 0;
        s += v[j];
    }
    sh[t] = s;
    __syncthreads();
    for (int off = 1; off < 256; off <<= 1) {
        int x = (t >= off) ? sh[t - off] : 0;
        __syncthreads();
        sh[t] += x;
        __syncthreads();
    }
    int run = sh[t] - s;
#pragma unroll
    for (int j = 0; j < 4; j++) {
        int i = base + j;
        if (i < N) excl[i] = run;
        run += v[j];
    }
    if (t == 255) bsum[blockIdx.x] = sh[255];
}

__global__ __launch_bounds__(256) void k_scan2(const int* __restrict__ bsum, int* __restrict__ boff,
                                               int nb, int* __restrict__ rp_last) {
    __shared__ int sh[256];
    int t = threadIdx.x;
    int v = (t < nb) ? bsum[t] : 0;
    sh[t] = v;
    __syncthreads();
    for (int off = 1; off < 256; off <<= 1) {
        int x = (t >= off) ? sh[t - off] : 0;
        __syncthreads();
        sh[t] += x;
        __syncthreads();
    }
    if (t < nb) boff[t] = sh[t] - v;
    if (t == 255) *rp_last = sh[255];
}

__global__ void k_scan3(int* __restrict__ rp, const int* __restrict__ boff, int* __restrict__ next, int N) {
    int i = blockIdx.x * 256 + threadIdx.x;
    if (i < N) {
        int v = rp[i] + boff[i >> 10];
        rp[i] = v;
        next[i] = v;
    }
}

// ---------------- fill: CSR scatter + precompute GAT weight per edge ----------------
__global__ void k_fill(const int* __restrict__ src, const int* __restrict__ dst, int* __restrict__ next,
                       const float* __restrict__ a_s, const float* __restrict__ a_d,
                       int2* __restrict__ es, int E) {
    int e = blockIdx.x * 256 + threadIdx.x;
    if (e < E) {
        int s = src[e], d = dst[e];
        float gl = a_s[s] + a_d[d];
        gl = gl >= 0.f ? gl : 0.2f * gl;      // LeakyReLU(0.2)
        float wg = __expf(gl);
        int p = atomicAdd(&next[d], 1);
        int2 v;
        v.x = s * 384;
        v.y = __float_as_int(wg);
        es[p] = v;
    }
}

// ---------------- fused edge phase: 16-lane group per node (4 nodes/wave) ----------------
// Group gathers one 256B row per load; intra-group 4-level shfl for the dot; no cross-group
// reduce; per-node prologue/epilogue amortized 4x across the wave's instruction stream.
// No max-subtraction (logits bounded; softmax shift-invariant; validated r1-r6).
__global__ __launch_bounds__(256) void k_edge(const int* __restrict__ rp, const int2* __restrict__ es,
                                              const u16* __restrict__ HKV, const u16* __restrict__ Q,
                                              const u16* __restrict__ R, const float* __restrict__ bias,
                                              float* __restrict__ out, int N) {
    const int n = (blockIdx.x * 256 + threadIdx.x) >> 4;   // one node per 16-lane group
    if (n >= N) return;
    const int l = threadIdx.x & 15;
    const int l8 = l * 8;

    u32x4 qv = *reinterpret_cast<const u32x4*>(Q + (size_t)n * 128 + l8);
    float qf[8];
#pragma unroll
    for (int i = 0; i < 4; i++) { qf[2 * i] = blo(qv[i]); qf[2 * i + 1] = bhi(qv[i]); }

    const int beg = rp[n], end = rp[n + 1];

    float ag[8] = {0.f, 0.f, 0.f, 0.f, 0.f, 0.f, 0.f, 0.f};
    float at[8] = {0.f, 0.f, 0.f, 0.f, 0.f, 0.f, 0.f, 0.f};
    float zg = 0.f, zt = 0.f;

    for (int p = beg; p < end; p++) {
        int2 e0 = es[p];                              // group-uniform broadcast load
        const u16* base = HKV + e0.x + l8;
        u32x4 h0 = *reinterpret_cast<const u32x4*>(base);
        u32x4 k0 = *reinterpret_cast<const u32x4*>(base + 128);
        u32x4 v0 = *reinterpret_cast<const u32x4*>(base + 256);
        float wg0 = __int_as_float(e0.y);

        float d0 = 0.f;
#pragma unroll
        for (int i = 0; i < 4; i++) {
            d0 = fmaf(qf[2 * i], blo(k0[i]), d0);
            d0 = fmaf(qf[2 * i + 1], bhi(k0[i]), d0);
        }
        d0 += __shfl_xor(d0, 1);
        d0 += __shfl_xor(d0, 2);
        d0 += __shfl_xor(d0, 4);
        d0 += __shfl_xor(d0, 8);
        float wt0 = __expf(d0);                       // Q pre-scaled by 1/sqrt(128)

#pragma unroll
        for (int i = 0; i < 4; i++) {
            ag[2 * i]     = fmaf(wg0, blo(h0[i]), ag[2 * i]);
            ag[2 * i + 1] = fmaf(wg0, bhi(h0[i]), ag[2 * i + 1]);
            at[2 * i]     = fmaf(wt0, blo(v0[i]), at[2 * i]);
            at[2 * i + 1] = fmaf(wt0, bhi(v0[i]), at[2 * i + 1]);
        }
        zg += wg0;
        zt += wt0;
    }

    float ig = 1.f / (zg + 1e-16f), it = 1.f / (zt + 1e-16f);
    u32x4 rv = *reinterpret_cast<const u32x4*>(R + (size_t)n * 128 + l8);
    float4 b0 = *reinterpret_cast<const float4*>(bias + l8);
    float4 b1 = *reinterpret_cast<const float4*>(bias + l8 + 4);
    float bb[8] = {b0.x, b0.y, b0.z, b0.w, b1.x, b1.y, b1.z, b1.w};

    float o[8];
    float ss = 0.f;
#pragma unroll
    for (int i = 0; i < 4; i++) {
        float r0 = blo(rv[i]), r1 = bhi(rv[i]);
        float g0 = fmaxf(ag[2 * i] * ig + bb[2 * i], 0.f);
        float g1 = fmaxf(ag[2 * i + 1] * ig + bb[2 * i + 1], 0.f);
        o[2 * i] = g0 + at[2 * i] * it + r0;
        o[2 * i + 1] = g1 + at[2 * i + 1] * it + r1;
        ss += o[2 * i] * o[2 * i] + o[2 * i + 1] * o[2 * i + 1];
    }
    ss += __shfl_xor(ss, 1);
    ss += __shfl_xor(ss, 2);
    ss += __shfl_xor(ss, 4);
    ss += __shfl_xor(ss, 8);
    float inv = 1.f / fmaxf(sqrtf(ss), 1e-12f);

    float4 s0 = {o[0] * inv, o[1] * inv, o[2] * inv, o[3] * inv};
    float4 s1 = {o[4] * inv, o[5] * inv, o[6] * inv, o[7] * inv};
    float* op = out + (size_t)n * 128 + l8;
    *reinterpret_cast<float4*>(op) = s0;
    *reinterpret_cast<float4*>(op + 4) = s1;
}

// ---------------- host launcher ----------------
extern "C" void kernel_launch(void* const* d_in, const int* in_sizes, int n_in,
                              void* d_out, int out_size, void* d_ws, size_t ws_size,
                              hipStream_t stream) {
    const int* edge = (const int*)d_in[1];
    const float* emb = (const float*)d_in[2];
    const float* gat_W = (const float*)d_in[3];
    const float* a_src = (const float*)d_in[4];
    const float* a_dst = (const float*)d_in[5];
    const float* bias = (const float*)d_in[6];
    const float* Wq = (const float*)d_in[7];
    const float* Wk = (const float*)d_in[8];
    const float* Wv = (const float*)d_in[9];
    const float* Wr = (const float*)d_in[10];

    const int E = in_sizes[1] / 2;
    const int N = in_sizes[2] / 128;
    const int* src = edge;
    const int* dst = edge + E;
    float* out = (float*)d_out;

    char* w = (char*)d_ws;
    auto alloc = [&](size_t bytes) -> char* {
        char* p = w;
        w += (bytes + 255) & ~(size_t)255;
        return p;
    };
    u16* HKV = (u16*)alloc((size_t)N * 384 * 2);    // [n][H|K|V][128]
    u16* Q   = (u16*)alloc((size_t)N * 128 * 2);
    u16* R   = (u16*)alloc((size_t)N * 128 * 2);
    u16* Xb  = (u16*)alloc((size_t)N * 128 * 2);
    u16* Wt  = (u16*)alloc(5 * 128 * 128 * 2);
    float* a_s = (float*)alloc((size_t)N * 4);
    float* a_d = (float*)alloc((size_t)N * 4);
    int* cnt  = (int*)alloc((size_t)N * 4);
    int* rp   = (int*)alloc((size_t)(N + 1) * 4);
    int* nxt  = (int*)alloc((size_t)N * 4);
    int* bsum = (int*)alloc(1024);
    int* boff = (int*)alloc(1024);
    int2* es  = (int2*)alloc((size_t)E * 8);

    const int NX = N * 128;
    const int nxc = (NX + 2047) / 2048;
    const int nb = (N + 1023) / 1024;
    const int nhist = (E + 255) / 256;

    hipMemsetAsync(cnt, 0, (size_t)N * 4, stream);
    k_ph<<<nxc + 320 + nhist, 256, 0, stream>>>(emb, Xb, NX, gat_W, Wq, Wk, Wv, Wr, Wt, dst, cnt, E, nxc);
    k_gemm<<<dim3((N + 127) / 128, 5), 512, 0, stream>>>(Xb, Wt, HKV, Q, R, a_src, a_dst, a_s, a_d, N);
    k_scan1<<<nb, 256, 0, stream>>>(cnt, rp, bsum, N);
    k_scan2<<<1, 256, 0, stream>>>(bsum, boff, nb, rp + N);
    k_scan3<<<(N + 255) / 256, 256, 0, stream>>>(rp, boff, nxt, N);
    k_fill<<<nhist, 256, 0, stream>>>(src, dst, nxt, a_s, a_d, es, E);
    k_edge<<<(N * 16 + 255) / 256, 256, 0, stream>>>(rp, es, HKV, Q, R, bias, out, N);
}

// Round 8
// 213.275 us; speedup vs baseline: 1.4075x; 1.0043x over previous
//
#include <hip/hip_runtime.h>

typedef unsigned short u16;
typedef unsigned int   u32;
typedef __attribute__((ext_vector_type(8))) short short8;
typedef __attribute__((ext_vector_type(4))) unsigned int u32x4;
typedef __attribute__((ext_vector_type(4))) float f32x4;

__device__ __forceinline__ u16 f2b(float f) {
    u32 u = __float_as_uint(f);
    u32 r = (u + 0x7fffu + ((u >> 16) & 1u)) >> 16;   // round-to-nearest-even
    return (u16)r;
}
__device__ __forceinline__ float blo(u32 w) { return __uint_as_float(w << 16); }
__device__ __forceinline__ float bhi(u32 w) { return __uint_as_float(w & 0xffff0000u); }

// ---------------- prep: X->bf16 convert, weight transpose+bf16, edge histogram ----------------
__global__ void k_ph(const float* __restrict__ X, u16* __restrict__ Xb, int NX,
                     const float* __restrict__ W0, const float* __restrict__ W1,
                     const float* __restrict__ W2, const float* __restrict__ W3,
                     const float* __restrict__ W4, u16* __restrict__ Wt,
                     const int* __restrict__ dst, int* __restrict__ cnt, int E, int nxc) {
    int b = blockIdx.x, t = threadIdx.x;
    if (b < nxc) {
        int i0 = b * 2048 + t * 8;
        if (i0 + 8 <= NX) {
            float4 f0 = *reinterpret_cast<const float4*>(X + i0);
            float4 f1 = *reinterpret_cast<const float4*>(X + i0 + 4);
            short8 vv;
            vv[0] = (short)f2b(f0.x); vv[1] = (short)f2b(f0.y);
            vv[2] = (short)f2b(f0.z); vv[3] = (short)f2b(f0.w);
            vv[4] = (short)f2b(f1.x); vv[5] = (short)f2b(f1.y);
            vv[6] = (short)f2b(f1.z); vv[7] = (short)f2b(f1.w);
            *reinterpret_cast<short8*>(Xb + i0) = vv;
        }
    } else if (b < nxc + 320) {
        int id = (b - nxc) * 256 + t;
        if (id < 5 * 16384) {
            int g = id >> 14, j = (id >> 7) & 127, k = id & 127;
            const float* W = g == 0 ? W0 : g == 1 ? W1 : g == 2 ? W2 : g == 3 ? W3 : W4;
            Wt[id] = f2b(W[k * 128 + j]);
        }
    } else {
        int e = (b - nxc - 320) * 256 + t;
        if (e < E) atomicAdd(&cnt[dst[e]], 1);
    }
}

// ---------------- GEMM: grid (ceil(N/128), 5), 512 threads, A+B in LDS (69.6KB) ----------------
__global__ __launch_bounds__(512) void k_gemm(const u16* __restrict__ Xb, const u16* __restrict__ Wt,
                                              u16* __restrict__ HKV, u16* __restrict__ Q, u16* __restrict__ R,
                                              const float* __restrict__ asrc, const float* __restrict__ adst,
                                              float* __restrict__ a_s, float* __restrict__ a_d, int N) {
    __shared__ u16 As[128][136];
    __shared__ u16 Bs[128][136];
    const int tid = threadIdx.x;
    const int g = blockIdx.y;
    const int row0 = blockIdx.x * 128;
    const u16* wt = Wt + g * 16384;

    for (int c = tid; c < 128 * 16; c += 512) {
        int r = c >> 4, col8 = (c & 15) * 8;
        int grow = row0 + r;
        short8 av = {0, 0, 0, 0, 0, 0, 0, 0};
        if (grow < N) av = *reinterpret_cast<const short8*>(Xb + (size_t)grow * 128 + col8);
        *reinterpret_cast<short8*>(&As[r][col8]) = av;
        *reinterpret_cast<short8*>(&Bs[r][col8]) =
            *reinterpret_cast<const short8*>(wt + r * 128 + col8);
    }
    __syncthreads();

    const int wid = tid >> 6, lane = tid & 63;
    const int l15 = lane & 15;
    const int arow = wid * 16 + l15;
    const int kg = (lane >> 4) * 8;

    short8 af[4];
#pragma unroll
    for (int kc = 0; kc < 4; kc++)
        af[kc] = *reinterpret_cast<const short8*>(&As[arow][kc * 32 + kg]);

    const int rbase = row0 + wid * 16 + ((lane >> 4) << 2);
    const float isd = 0.08838834764831845f;   // 1/sqrt(128)

    u16* outp;
    int stride;
    float osc = 1.f;
    if (g == 0)      { outp = HKV;       stride = 384; }
    else if (g == 1) { outp = Q;         stride = 128; osc = isd; }
    else if (g == 2) { outp = HKV + 128; stride = 384; }
    else if (g == 3) { outp = HKV + 256; stride = 384; }
    else             { outp = R;         stride = 128; }

    float ps[4] = {0.f, 0.f, 0.f, 0.f};
    float pd[4] = {0.f, 0.f, 0.f, 0.f};

#pragma unroll
    for (int c = 0; c < 8; c++) {
        const int bcol = c * 16 + l15;
        f32x4 acc = {0.f, 0.f, 0.f, 0.f};
#pragma unroll
        for (int kc = 0; kc < 4; kc++) {
            short8 bf = *reinterpret_cast<const short8*>(&Bs[bcol][kc * 32 + kg]);
            acc = __builtin_amdgcn_mfma_f32_16x16x32_bf16(af[kc], bf, acc, 0, 0, 0);
        }
#pragma unroll
        for (int r = 0; r < 4; r++) {
            int grow = rbase + r;
            if (grow < N) outp[(size_t)grow * stride + bcol] = f2b(acc[r] * osc);
        }
        if (g == 0) {
            float vs = asrc[bcol], vd = adst[bcol];
#pragma unroll
            for (int r = 0; r < 4; r++) {
                ps[r] += acc[r] * vs;
                pd[r] += acc[r] * vd;
            }
        }
    }
    if (g == 0) {
#pragma unroll
        for (int off = 1; off < 16; off <<= 1) {
#pragma unroll
            for (int r = 0; r < 4; r++) {
                ps[r] += __shfl_xor(ps[r], off);
                pd[r] += __shfl_xor(pd[r], off);
            }
        }
        if (l15 == 0) {
#pragma unroll
            for (int r = 0; r < 4; r++) {
                int grow = rbase + r;
                if (grow < N) { a_s[grow] = ps[r]; a_d[grow] = pd[r]; }
            }
        }
    }
}

// ---------------- CSR scan chain ----------------
__global__ __launch_bounds__(256) void k_scan1(const int* __restrict__ cnt, int* __restrict__ excl,
                                               int* __restrict__ bsum, int N) {
    __shared__ int sh[256];
    int t = threadIdx.x;
    int base = blockIdx.x * 1024 + t * 4;
    int v[4], s = 0;
#pragma unroll
    for (int j = 0; j < 4; j++) {
        int i = base + j;
        v[j] = (i < N) ? cnt[i] : 0;
        s += v[j];
    }
    sh[t] = s;
    __syncthreads();
    for (int off = 1; off < 256; off <<= 1) {
        int x = (t >= off) ? sh[t - off] : 0;
        __syncthreads();
        sh[t] += x;
        __syncthreads();
    }
    int run = sh[t] - s;
#pragma unroll
    for (int j = 0; j < 4; j++) {
        int i = base + j;
        if (i < N) excl[i] = run;
        run += v[j];
    }
    if (t == 255) bsum[blockIdx.x] = sh[255];
}

__global__ __launch_bounds__(256) void k_scan2(const int* __restrict__ bsum, int* __restrict__ boff,
                                               int nb, int* __restrict__ rp_last) {
    __shared__ int sh[256];
    int t = threadIdx.x;
    int v = (t < nb) ? bsum[t] : 0;
    sh[t] = v;
    __syncthreads();
    for (int off = 1; off < 256; off <<= 1) {
        int x = (t >= off) ? sh[t - off] : 0;
        __syncthreads();
        sh[t] += x;
        __syncthreads();
    }
    if (t < nb) boff[t] = sh[t] - v;
    if (t == 255) *rp_last = sh[255];
}

__global__ void k_scan3(int* __restrict__ rp, const int* __restrict__ boff, int* __restrict__ next, int N) {
    int i = blockIdx.x * 256 + threadIdx.x;
    if (i < N) {
        int v = rp[i] + boff[i >> 10];
        rp[i] = v;
        next[i] = v;
    }
}

// ---------------- fill: CSR scatter + precompute GAT weight per edge ----------------
__global__ void k_fill(const int* __restrict__ src, const int* __restrict__ dst, int* __restrict__ next,
                       const float* __restrict__ a_s, const float* __restrict__ a_d,
                       int2* __restrict__ es, int E) {
    int e = blockIdx.x * 256 + threadIdx.x;
    if (e < E) {
        int s = src[e], d = dst[e];
        float gl = a_s[s] + a_d[d];
        gl = gl >= 0.f ? gl : 0.2f * gl;      // LeakyReLU(0.2)
        float wg = __expf(gl);
        int p = atomicAdd(&next[d], 1);
        int2 v;
        v.x = s * 384;
        v.y = __float_as_int(wg);
        es[p] = v;
    }
}

// ---------------- fused edge phase: 16-lane group per node, es lane-prefetch, 2x unroll ----------
// Lane l preloads es[beg+l] (covers deg<=16; rare tail falls back to direct loads). Edge
// address/weight broadcast via __shfl(.,j,16) — no dependent es load in the loop; unroll-2
// keeps 6 gathers in flight per group. No max-subtraction (validated r1-r7).
__global__ __launch_bounds__(256) void k_edge(const int* __restrict__ rp, const int2* __restrict__ es,
                                              const u16* __restrict__ HKV, const u16* __restrict__ Q,
                                              const u16* __restrict__ R, const float* __restrict__ bias,
                                              float* __restrict__ out, int N) {
    const int n = (blockIdx.x * 256 + threadIdx.x) >> 4;   // one node per 16-lane group
    if (n >= N) return;
    const int l = threadIdx.x & 15;
    const int l8 = l * 8;

    u32x4 qv = *reinterpret_cast<const u32x4*>(Q + (size_t)n * 128 + l8);
    float qf[8];
#pragma unroll
    for (int i = 0; i < 4; i++) { qf[2 * i] = blo(qv[i]); qf[2 * i + 1] = bhi(qv[i]); }

    const int beg = rp[n], end = rp[n + 1];
    const int deg = end - beg;
    const int m = deg < 16 ? deg : 16;

    // lane-prefetch first 16 edge records (coalesced)
    int ex_l = 0;
    float ew_l = 0.f;
    if (l < m) {
        int2 el = es[beg + l];
        ex_l = el.x;
        ew_l = __int_as_float(el.y);
    }

    float ag[8] = {0.f, 0.f, 0.f, 0.f, 0.f, 0.f, 0.f, 0.f};
    float at[8] = {0.f, 0.f, 0.f, 0.f, 0.f, 0.f, 0.f, 0.f};
    float zg = 0.f, zt = 0.f;

    int j = 0;
    for (; j + 2 <= m; j += 2) {
        int ex0 = __shfl(ex_l, j, 16);
        int ex1 = __shfl(ex_l, j + 1, 16);
        float wg0 = __shfl(ew_l, j, 16);
        float wg1 = __shfl(ew_l, j + 1, 16);
        const u16* b0 = HKV + ex0 + l8;
        const u16* b1 = HKV + ex1 + l8;
        u32x4 h0 = *reinterpret_cast<const u32x4*>(b0);
        u32x4 k0 = *reinterpret_cast<const u32x4*>(b0 + 128);
        u32x4 v0 = *reinterpret_cast<const u32x4*>(b0 + 256);
        u32x4 h1 = *reinterpret_cast<const u32x4*>(b1);
        u32x4 k1 = *reinterpret_cast<const u32x4*>(b1 + 128);
        u32x4 v1 = *reinterpret_cast<const u32x4*>(b1 + 256);

        float d0 = 0.f, d1 = 0.f;
#pragma unroll
        for (int i = 0; i < 4; i++) {
            d0 = fmaf(qf[2 * i], blo(k0[i]), d0);
            d0 = fmaf(qf[2 * i + 1], bhi(k0[i]), d0);
            d1 = fmaf(qf[2 * i], blo(k1[i]), d1);
            d1 = fmaf(qf[2 * i + 1], bhi(k1[i]), d1);
        }
#pragma unroll
        for (int off = 1; off < 16; off <<= 1) {
            d0 += __shfl_xor(d0, off);
            d1 += __shfl_xor(d1, off);
        }
        float wt0 = __expf(d0), wt1 = __expf(d1);   // Q pre-scaled by 1/sqrt(128)

#pragma unroll
        for (int i = 0; i < 4; i++) {
            ag[2 * i]     = fmaf(wg0, blo(h0[i]), ag[2 * i]);
            ag[2 * i + 1] = fmaf(wg0, bhi(h0[i]), ag[2 * i + 1]);
            ag[2 * i]     = fmaf(wg1, blo(h1[i]), ag[2 * i]);
            ag[2 * i + 1] = fmaf(wg1, bhi(h1[i]), ag[2 * i + 1]);
            at[2 * i]     = fmaf(wt0, blo(v0[i]), at[2 * i]);
            at[2 * i + 1] = fmaf(wt0, bhi(v0[i]), at[2 * i + 1]);
            at[2 * i]     = fmaf(wt1, blo(v1[i]), at[2 * i]);
            at[2 * i + 1] = fmaf(wt1, bhi(v1[i]), at[2 * i + 1]);
        }
        zg += wg0 + wg1;
        zt += wt0 + wt1;
    }
    if (j < m) {
        int ex0 = __shfl(ex_l, j, 16);
        float wg0 = __shfl(ew_l, j, 16);
        const u16* b0 = HKV + ex0 + l8;
        u32x4 h0 = *reinterpret_cast<const u32x4*>(b0);
        u32x4 k0 = *reinterpret_cast<const u32x4*>(b0 + 128);
        u32x4 v0 = *reinterpret_cast<const u32x4*>(b0 + 256);
        float d0 = 0.f;
#pragma unroll
        for (int i = 0; i < 4; i++) {
            d0 = fmaf(qf[2 * i], blo(k0[i]), d0);
            d0 = fmaf(qf[2 * i + 1], bhi(k0[i]), d0);
        }
#pragma unroll
        for (int off = 1; off < 16; off <<= 1) d0 += __shfl_xor(d0, off);
        float wt0 = __expf(d0);
#pragma unroll
        for (int i = 0; i < 4; i++) {
            ag[2 * i]     = fmaf(wg0, blo(h0[i]), ag[2 * i]);
            ag[2 * i + 1] = fmaf(wg0, bhi(h0[i]), ag[2 * i + 1]);
            at[2 * i]     = fmaf(wt0, blo(v0[i]), at[2 * i]);
            at[2 * i + 1] = fmaf(wt0, bhi(v0[i]), at[2 * i + 1]);
        }
        zg += wg0;
        zt += wt0;
    }
    // rare tail: degree > 16
    for (int p = beg + 16; p < end; p++) {
        int2 e0 = es[p];
        const u16* b0 = HKV + e0.x + l8;
        u32x4 h0 = *reinterpret_cast<const u32x4*>(b0);
        u32x4 k0 = *reinterpret_cast<const u32x4*>(b0 + 128);
        u32x4 v0 = *reinterpret_cast<const u32x4*>(b0 + 256);
        float wg0 = __int_as_float(e0.y);
        float d0 = 0.f;
#pragma unroll
        for (int i = 0; i < 4; i++) {
            d0 = fmaf(qf[2 * i], blo(k0[i]), d0);
            d0 = fmaf(qf[2 * i + 1], bhi(k0[i]), d0);
        }
#pragma unroll
        for (int off = 1; off < 16; off <<= 1) d0 += __shfl_xor(d0, off);
        float wt0 = __expf(d0);
#pragma unroll
        for (int i = 0; i < 4; i++) {
            ag[2 * i]     = fmaf(wg0, blo(h0[i]), ag[2 * i]);
            ag[2 * i + 1] = fmaf(wg0, bhi(h0[i]), ag[2 * i + 1]);
            at[2 * i]     = fmaf(wt0, blo(v0[i]), at[2 * i]);
            at[2 * i + 1] = fmaf(wt0, bhi(v0[i]), at[2 * i + 1]);
        }
        zg += wg0;
        zt += wt0;
    }

    float ig = 1.f / (zg + 1e-16f), it = 1.f / (zt + 1e-16f);
    u32x4 rv = *reinterpret_cast<const u32x4*>(R + (size_t)n * 128 + l8);
    float4 b0 = *reinterpret_cast<const float4*>(bias + l8);
    float4 b1 = *reinterpret_cast<const float4*>(bias + l8 + 4);
    float bb[8] = {b0.x, b0.y, b0.z, b0.w, b1.x, b1.y, b1.z, b1.w};

    float o[8];
    float ss = 0.f;
#pragma unroll
    for (int i = 0; i < 4; i++) {
        float r0 = blo(rv[i]), r1 = bhi(rv[i]);
        float g0 = fmaxf(ag[2 * i] * ig + bb[2 * i], 0.f);
        float g1 = fmaxf(ag[2 * i + 1] * ig + bb[2 * i + 1], 0.f);
        o[2 * i] = g0 + at[2 * i] * it + r0;
        o[2 * i + 1] = g1 + at[2 * i + 1] * it + r1;
        ss += o[2 * i] * o[2 * i] + o[2 * i + 1] * o[2 * i + 1];
    }
    ss += __shfl_xor(ss, 1);
    ss += __shfl_xor(ss, 2);
    ss += __shfl_xor(ss, 4);
    ss += __shfl_xor(ss, 8);
    float inv = 1.f / fmaxf(sqrtf(ss), 1e-12f);

    float4 s0 = {o[0] * inv, o[1] * inv, o[2] * inv, o[3] * inv};
    float4 s1 = {o[4] * inv, o[5] * inv, o[6] * inv, o[7] * inv};
    float* op = out + (size_t)n * 128 + l8;
    *reinterpret_cast<float4*>(op) = s0;
    *reinterpret_cast<float4*>(op + 4) = s1;
}

// ---------------- host launcher ----------------
extern "C" void kernel_launch(void* const* d_in, const int* in_sizes, int n_in,
                              void* d_out, int out_size, void* d_ws, size_t ws_size,
                              hipStream_t stream) {
    const int* edge = (const int*)d_in[1];
    const float* emb = (const float*)d_in[2];
    const float* gat_W = (const float*)d_in[3];
    const float* a_src = (const float*)d_in[4];
    const float* a_dst = (const float*)d_in[5];
    const float* bias = (const float*)d_in[6];
    const float* Wq = (const float*)d_in[7];
    const float* Wk = (const float*)d_in[8];
    const float* Wv = (const float*)d_in[9];
    const float* Wr = (const float*)d_in[10];

    const int E = in_sizes[1] / 2;
    const int N = in_sizes[2] / 128;
    const int* src = edge;
    const int* dst = edge + E;
    float* out = (float*)d_out;

    char* w = (char*)d_ws;
    auto alloc = [&](size_t bytes) -> char* {
        char* p = w;
        w += (bytes + 255) & ~(size_t)255;
        return p;
    };
    u16* HKV = (u16*)alloc((size_t)N * 384 * 2);    // [n][H|K|V][128]
    u16* Q   = (u16*)alloc((size_t)N * 128 * 2);
    u16* R   = (u16*)alloc((size_t)N * 128 * 2);
    u16* Xb  = (u16*)alloc((size_t)N * 128 * 2);
    u16* Wt  = (u16*)alloc(5 * 128 * 128 * 2);
    float* a_s = (float*)alloc((size_t)N * 4);
    float* a_d = (float*)alloc((size_t)N * 4);
    int* cnt  = (int*)alloc((size_t)N * 4);
    int* rp   = (int*)alloc((size_t)(N + 1) * 4);
    int* nxt  = (int*)alloc((size_t)N * 4);
    int* bsum = (int*)alloc(1024);
    int* boff = (int*)alloc(1024);
    int2* es  = (int2*)alloc((size_t)E * 8);

    const int NX = N * 128;
    const int nxc = (NX + 2047) / 2048;
    const int nb = (N + 1023) / 1024;
    const int nhist = (E + 255) / 256;

    hipMemsetAsync(cnt, 0, (size_t)N * 4, stream);
    k_ph<<<nxc + 320 + nhist, 256, 0, stream>>>(emb, Xb, NX, gat_W, Wq, Wk, Wv, Wr, Wt, dst, cnt, E, nxc);
    k_gemm<<<dim3((N + 127) / 128, 5), 512, 0, stream>>>(Xb, Wt, HKV, Q, R, a_src, a_dst, a_s, a_d, N);
    k_scan1<<<nb, 256, 0, stream>>>(cnt, rp, bsum, N);
    k_scan2<<<1, 256, 0, stream>>>(bsum, boff, nb, rp + N);
    k_scan3<<<(N + 255) / 256, 256, 0, stream>>>(rp, boff, nxt, N);
    k_fill<<<nhist, 256, 0, stream>>>(src, dst, nxt, a_s, a_d, es, E);
    k_edge<<<(N * 16 + 255) / 256, 256, 0, stream>>>(rp, es, HKV, Q, R, bias, out, N);
}

// Round 9
// 208.802 us; speedup vs baseline: 1.4376x; 1.0214x over previous
//
#include <hip/hip_runtime.h>

typedef unsigned short u16;
typedef unsigned int   u32;
typedef __attribute__((ext_vector_type(8))) short short8;
typedef __attribute__((ext_vector_type(4))) unsigned int u32x4;
typedef __attribute__((ext_vector_type(4))) float f32x4;

__device__ __forceinline__ u16 f2b(float f) {
    u32 u = __float_as_uint(f);
    u32 r = (u + 0x7fffu + ((u >> 16) & 1u)) >> 16;   // round-to-nearest-even
    return (u16)r;
}
__device__ __forceinline__ float blo(u32 w) { return __uint_as_float(w << 16); }
__device__ __forceinline__ float bhi(u32 w) { return __uint_as_float(w & 0xffff0000u); }

// ---------------- prep: X->bf16 convert, weight transpose+bf16, edge histogram ----------------
__global__ void k_ph(const float* __restrict__ X, u16* __restrict__ Xb, int NX,
                     const float* __restrict__ W0, const float* __restrict__ W1,
                     const float* __restrict__ W2, const float* __restrict__ W3,
                     const float* __restrict__ W4, u16* __restrict__ Wt,
                     const int* __restrict__ dst, int* __restrict__ cnt, int E, int nxc) {
    int b = blockIdx.x, t = threadIdx.x;
    if (b < nxc) {
        int i0 = b * 2048 + t * 8;
        if (i0 + 8 <= NX) {
            float4 f0 = *reinterpret_cast<const float4*>(X + i0);
            float4 f1 = *reinterpret_cast<const float4*>(X + i0 + 4);
            short8 vv;
            vv[0] = (short)f2b(f0.x); vv[1] = (short)f2b(f0.y);
            vv[2] = (short)f2b(f0.z); vv[3] = (short)f2b(f0.w);
            vv[4] = (short)f2b(f1.x); vv[5] = (short)f2b(f1.y);
            vv[6] = (short)f2b(f1.z); vv[7] = (short)f2b(f1.w);
            *reinterpret_cast<short8*>(Xb + i0) = vv;
        }
    } else if (b < nxc + 320) {
        int id = (b - nxc) * 256 + t;
        if (id < 5 * 16384) {
            int g = id >> 14, j = (id >> 7) & 127, k = id & 127;
            const float* W = g == 0 ? W0 : g == 1 ? W1 : g == 2 ? W2 : g == 3 ? W3 : W4;
            Wt[id] = f2b(W[k * 128 + j]);
        }
    } else {
        int e = (b - nxc - 320) * 256 + t;
        if (e < E) atomicAdd(&cnt[dst[e]], 1);
    }
}

// ---------------- GEMM v4: B-only LDS (34.8KB -> 4 blocks/CU), A direct from L3-resident Xb,
// paired-column MFMA -> packed dword stores. g = blockIdx.y; Q pre-scaled; nt-stores for Q/R.
__global__ __launch_bounds__(512) void k_gemm(const u16* __restrict__ Xb, const u16* __restrict__ Wt,
                                              u16* __restrict__ HKV, u16* __restrict__ Q, u16* __restrict__ R,
                                              const float* __restrict__ asrc, const float* __restrict__ adst,
                                              float* __restrict__ a_s, float* __restrict__ a_d, int N) {
    __shared__ u16 Bs[128][136];
    const int tid = threadIdx.x;
    const int g = blockIdx.y;
    const int row0 = blockIdx.x * 128;
    const u16* wt = Wt + g * 16384;

    for (int c = tid; c < 128 * 16; c += 512) {
        int r = c >> 4, col8 = (c & 15) * 8;
        *reinterpret_cast<short8*>(&Bs[r][col8]) =
            *reinterpret_cast<const short8*>(wt + r * 128 + col8);
    }

    const int wid = tid >> 6, lane = tid & 63;
    const int l15 = lane & 15;
    const int kg = (lane >> 4) * 8;
    const int arow = row0 + wid * 16 + l15;

    short8 af[4];
    if (arow < N) {
#pragma unroll
        for (int kc = 0; kc < 4; kc++)
            af[kc] = *reinterpret_cast<const short8*>(Xb + (size_t)arow * 128 + kc * 32 + kg);
    } else {
        short8 z = {0, 0, 0, 0, 0, 0, 0, 0};
#pragma unroll
        for (int kc = 0; kc < 4; kc++) af[kc] = z;
    }
    __syncthreads();

    const int rbase = row0 + wid * 16 + ((lane >> 4) << 2);
    const float isd = 0.08838834764831845f;   // 1/sqrt(128)

    u16* outp;
    int stride;
    float osc = 1.f;
    bool nts = false;
    if (g == 0)      { outp = HKV;       stride = 384; }
    else if (g == 1) { outp = Q;         stride = 128; osc = isd; nts = true; }
    else if (g == 2) { outp = HKV + 128; stride = 384; }
    else if (g == 3) { outp = HKV + 256; stride = 384; }
    else             { outp = R;         stride = 128; nts = true; }

    float ps[4] = {0.f, 0.f, 0.f, 0.f};
    float pd[4] = {0.f, 0.f, 0.f, 0.f};

#pragma unroll
    for (int c2 = 0; c2 < 4; c2++) {
        const int col0 = c2 * 32 + 2 * l15;     // even col; lane also owns col0+1
        f32x4 acc0 = {0.f, 0.f, 0.f, 0.f};
        f32x4 acc1 = {0.f, 0.f, 0.f, 0.f};
#pragma unroll
        for (int kc = 0; kc < 4; kc++) {
            short8 bf0 = *reinterpret_cast<const short8*>(&Bs[col0][kc * 32 + kg]);
            short8 bf1 = *reinterpret_cast<const short8*>(&Bs[col0 + 1][kc * 32 + kg]);
            acc0 = __builtin_amdgcn_mfma_f32_16x16x32_bf16(af[kc], bf0, acc0, 0, 0, 0);
            acc1 = __builtin_amdgcn_mfma_f32_16x16x32_bf16(af[kc], bf1, acc1, 0, 0, 0);
        }
#pragma unroll
        for (int r = 0; r < 4; r++) {
            int grow = rbase + r;
            if (grow < N) {
                u32 pk = (u32)f2b(acc0[r] * osc) | ((u32)f2b(acc1[r] * osc) << 16);
                u32* dst32 = reinterpret_cast<u32*>(outp + (size_t)grow * stride + col0);
                if (nts) __builtin_nontemporal_store(pk, dst32);
                else *dst32 = pk;
            }
        }
        if (g == 0) {
            float2 vs = *reinterpret_cast<const float2*>(asrc + col0);
            float2 vd = *reinterpret_cast<const float2*>(adst + col0);
#pragma unroll
            for (int r = 0; r < 4; r++) {
                ps[r] += acc0[r] * vs.x + acc1[r] * vs.y;
                pd[r] += acc0[r] * vd.x + acc1[r] * vd.y;
            }
        }
    }
    if (g == 0) {
#pragma unroll
        for (int off = 1; off < 16; off <<= 1) {
#pragma unroll
            for (int r = 0; r < 4; r++) {
                ps[r] += __shfl_xor(ps[r], off);
                pd[r] += __shfl_xor(pd[r], off);
            }
        }
        if (l15 == 0) {
#pragma unroll
            for (int r = 0; r < 4; r++) {
                int grow = rbase + r;
                if (grow < N) { a_s[grow] = ps[r]; a_d[grow] = pd[r]; }
            }
        }
    }
}

// ---------------- CSR scan chain ----------------
__global__ __launch_bounds__(256) void k_scan1(const int* __restrict__ cnt, int* __restrict__ excl,
                                               int* __restrict__ bsum, int N) {
    __shared__ int sh[256];
    int t = threadIdx.x;
    int base = blockIdx.x * 1024 + t * 4;
    int v[4], s = 0;
#pragma unroll
    for (int j = 0; j < 4; j++) {
        int i = base + j;
        v[j] = (i < N) ? cnt[i] : 0;
        s += v[j];
    }
    sh[t] = s;
    __syncthreads();
    for (int off = 1; off < 256; off <<= 1) {
        int x = (t >= off) ? sh[t - off] : 0;
        __syncthreads();
        sh[t] += x;
        __syncthreads();
    }
    int run = sh[t] - s;
#pragma unroll
    for (int j = 0; j < 4; j++) {
        int i = base + j;
        if (i < N) excl[i] = run;
        run += v[j];
    }
    if (t == 255) bsum[blockIdx.x] = sh[255];
}

__global__ __launch_bounds__(256) void k_scan2(const int* __restrict__ bsum, int* __restrict__ boff,
                                               int nb, int* __restrict__ rp_last) {
    __shared__ int sh[256];
    int t = threadIdx.x;
    int v = (t < nb) ? bsum[t] : 0;
    sh[t] = v;
    __syncthreads();
    for (int off = 1; off < 256; off <<= 1) {
        int x = (t >= off) ? sh[t - off] : 0;
        __syncthreads();
        sh[t] += x;
        __syncthreads();
    }
    if (t < nb) boff[t] = sh[t] - v;
    if (t == 255) *rp_last = sh[255];
}

__global__ void k_scan3(int* __restrict__ rp, const int* __restrict__ boff, int* __restrict__ next, int N) {
    int i = blockIdx.x * 256 + threadIdx.x;
    if (i < N) {
        int v = rp[i] + boff[i >> 10];
        rp[i] = v;
        next[i] = v;
    }
}

// ---------------- fill: CSR scatter + precompute GAT weight per edge ----------------
__global__ void k_fill(const int* __restrict__ src, const int* __restrict__ dst, int* __restrict__ next,
                       const float* __restrict__ a_s, const float* __restrict__ a_d,
                       int2* __restrict__ es, int E) {
    int e = blockIdx.x * 256 + threadIdx.x;
    if (e < E) {
        int s = src[e], d = dst[e];
        float gl = a_s[s] + a_d[d];
        gl = gl >= 0.f ? gl : 0.2f * gl;      // LeakyReLU(0.2)
        float wg = __expf(gl);
        int p = atomicAdd(&next[d], 1);
        int2 v;
        v.x = s * 384;
        v.y = __float_as_int(wg);
        es[p] = v;
    }
}

// ---------------- fused edge phase: 16-lane group per node, es lane-prefetch, nt hints ----------
// Streaming operands (Q, R, es, out) use nontemporal hints so L2/L3 keep the HKV gather
// working set. No max-subtraction (validated r1-r8).
__global__ __launch_bounds__(256) void k_edge(const int* __restrict__ rp, const int2* __restrict__ es,
                                              const u16* __restrict__ HKV, const u16* __restrict__ Q,
                                              const u16* __restrict__ R, const float* __restrict__ bias,
                                              float* __restrict__ out, int N) {
    const int n = (blockIdx.x * 256 + threadIdx.x) >> 4;   // one node per 16-lane group
    if (n >= N) return;
    const int l = threadIdx.x & 15;
    const int l8 = l * 8;

    u32x4 qv = __builtin_nontemporal_load(reinterpret_cast<const u32x4*>(Q + (size_t)n * 128 + l8));
    float qf[8];
#pragma unroll
    for (int i = 0; i < 4; i++) { qf[2 * i] = blo(qv[i]); qf[2 * i + 1] = bhi(qv[i]); }

    const int beg = rp[n], end = rp[n + 1];
    const int deg = end - beg;
    const int m = deg < 16 ? deg : 16;

    // lane-prefetch first 16 edge records (coalesced, read-once -> nt)
    int ex_l = 0;
    float ew_l = 0.f;
    if (l < m) {
        long long ev = __builtin_nontemporal_load(reinterpret_cast<const long long*>(es) + beg + l);
        ex_l = (int)(u32)ev;
        ew_l = __int_as_float((int)(ev >> 32));
    }

    float ag[8] = {0.f, 0.f, 0.f, 0.f, 0.f, 0.f, 0.f, 0.f};
    float at[8] = {0.f, 0.f, 0.f, 0.f, 0.f, 0.f, 0.f, 0.f};
    float zg = 0.f, zt = 0.f;

    for (int j = 0; j < m; j++) {
        int ex0 = __shfl(ex_l, j, 16);
        float wg0 = __shfl(ew_l, j, 16);
        const u16* b0 = HKV + ex0 + l8;
        u32x4 h0 = *reinterpret_cast<const u32x4*>(b0);
        u32x4 k0 = *reinterpret_cast<const u32x4*>(b0 + 128);
        u32x4 v0 = *reinterpret_cast<const u32x4*>(b0 + 256);

        float d0 = 0.f;
#pragma unroll
        for (int i = 0; i < 4; i++) {
            d0 = fmaf(qf[2 * i], blo(k0[i]), d0);
            d0 = fmaf(qf[2 * i + 1], bhi(k0[i]), d0);
        }
        d0 += __shfl_xor(d0, 1);
        d0 += __shfl_xor(d0, 2);
        d0 += __shfl_xor(d0, 4);
        d0 += __shfl_xor(d0, 8);
        float wt0 = __expf(d0);                       // Q pre-scaled by 1/sqrt(128)

#pragma unroll
        for (int i = 0; i < 4; i++) {
            ag[2 * i]     = fmaf(wg0, blo(h0[i]), ag[2 * i]);
            ag[2 * i + 1] = fmaf(wg0, bhi(h0[i]), ag[2 * i + 1]);
            at[2 * i]     = fmaf(wt0, blo(v0[i]), at[2 * i]);
            at[2 * i + 1] = fmaf(wt0, bhi(v0[i]), at[2 * i + 1]);
        }
        zg += wg0;
        zt += wt0;
    }
    // rare tail: degree > 16
    for (int p = beg + 16; p < end; p++) {
        int2 e0 = es[p];
        const u16* b0 = HKV + e0.x + l8;
        u32x4 h0 = *reinterpret_cast<const u32x4*>(b0);
        u32x4 k0 = *reinterpret_cast<const u32x4*>(b0 + 128);
        u32x4 v0 = *reinterpret_cast<const u32x4*>(b0 + 256);
        float wg0 = __int_as_float(e0.y);
        float d0 = 0.f;
#pragma unroll
        for (int i = 0; i < 4; i++) {
            d0 = fmaf(qf[2 * i], blo(k0[i]), d0);
            d0 = fmaf(qf[2 * i + 1], bhi(k0[i]), d0);
        }
#pragma unroll
        for (int off = 1; off < 16; off <<= 1) d0 += __shfl_xor(d0, off);
        float wt0 = __expf(d0);
#pragma unroll
        for (int i = 0; i < 4; i++) {
            ag[2 * i]     = fmaf(wg0, blo(h0[i]), ag[2 * i]);
            ag[2 * i + 1] = fmaf(wg0, bhi(h0[i]), ag[2 * i + 1]);
            at[2 * i]     = fmaf(wt0, blo(v0[i]), at[2 * i]);
            at[2 * i + 1] = fmaf(wt0, bhi(v0[i]), at[2 * i + 1]);
        }
        zg += wg0;
        zt += wt0;
    }

    float ig = 1.f / (zg + 1e-16f), it = 1.f / (zt + 1e-16f);
    u32x4 rv = __builtin_nontemporal_load(reinterpret_cast<const u32x4*>(R + (size_t)n * 128 + l8));
    float4 b0 = *reinterpret_cast<const float4*>(bias + l8);
    float4 b1 = *reinterpret_cast<const float4*>(bias + l8 + 4);
    float bb[8] = {b0.x, b0.y, b0.z, b0.w, b1.x, b1.y, b1.z, b1.w};

    float o[8];
    float ss = 0.f;
#pragma unroll
    for (int i = 0; i < 4; i++) {
        float r0 = blo(rv[i]), r1 = bhi(rv[i]);
        float g0 = fmaxf(ag[2 * i] * ig + bb[2 * i], 0.f);
        float g1 = fmaxf(ag[2 * i + 1] * ig + bb[2 * i + 1], 0.f);
        o[2 * i] = g0 + at[2 * i] * it + r0;
        o[2 * i + 1] = g1 + at[2 * i + 1] * it + r1;
        ss += o[2 * i] * o[2 * i] + o[2 * i + 1] * o[2 * i + 1];
    }
    ss += __shfl_xor(ss, 1);
    ss += __shfl_xor(ss, 2);
    ss += __shfl_xor(ss, 4);
    ss += __shfl_xor(ss, 8);
    float inv = 1.f / fmaxf(sqrtf(ss), 1e-12f);

    f32x4 s0 = {o[0] * inv, o[1] * inv, o[2] * inv, o[3] * inv};
    f32x4 s1 = {o[4] * inv, o[5] * inv, o[6] * inv, o[7] * inv};
    float* op = out + (size_t)n * 128 + l8;
    __builtin_nontemporal_store(s0, reinterpret_cast<f32x4*>(op));
    __builtin_nontemporal_store(s1, reinterpret_cast<f32x4*>(op + 4));
}

// ---------------- host launcher ----------------
extern "C" void kernel_launch(void* const* d_in, const int* in_sizes, int n_in,
                              void* d_out, int out_size, void* d_ws, size_t ws_size,
                              hipStream_t stream) {
    const int* edge = (const int*)d_in[1];
    const float* emb = (const float*)d_in[2];
    const float* gat_W = (const float*)d_in[3];
    const float* a_src = (const float*)d_in[4];
    const float* a_dst = (const float*)d_in[5];
    const float* bias = (const float*)d_in[6];
    const float* Wq = (const float*)d_in[7];
    const float* Wk = (const float*)d_in[8];
    const float* Wv = (const float*)d_in[9];
    const float* Wr = (const float*)d_in[10];

    const int E = in_sizes[1] / 2;
    const int N = in_sizes[2] / 128;
    const int* src = edge;
    const int* dst = edge + E;
    float* out = (float*)d_out;

    char* w = (char*)d_ws;
    auto alloc = [&](size_t bytes) -> char* {
        char* p = w;
        w += (bytes + 255) & ~(size_t)255;
        return p;
    };
    u16* HKV = (u16*)alloc((size_t)N * 384 * 2);    // [n][H|K|V][128]
    u16* Q   = (u16*)alloc((size_t)N * 128 * 2);
    u16* R   = (u16*)alloc((size_t)N * 128 * 2);
    u16* Xb  = (u16*)alloc((size_t)N * 128 * 2);
    u16* Wt  = (u16*)alloc(5 * 128 * 128 * 2);
    float* a_s = (float*)alloc((size_t)N * 4);
    float* a_d = (float*)alloc((size_t)N * 4);
    int* cnt  = (int*)alloc((size_t)N * 4);
    int* rp   = (int*)alloc((size_t)(N + 1) * 4);
    int* nxt  = (int*)alloc((size_t)N * 4);
    int* bsum = (int*)alloc(1024);
    int* boff = (int*)alloc(1024);
    int2* es  = (int2*)alloc((size_t)E * 8);

    const int NX = N * 128;
    const int nxc = (NX + 2047) / 2048;
    const int nb = (N + 1023) / 1024;
    const int nhist = (E + 255) / 256;

    hipMemsetAsync(cnt, 0, (size_t)N * 4, stream);
    k_ph<<<nxc + 320 + nhist, 256, 0, stream>>>(emb, Xb, NX, gat_W, Wq, Wk, Wv, Wr, Wt, dst, cnt, E, nxc);
    k_gemm<<<dim3((N + 127) / 128, 5), 512, 0, stream>>>(Xb, Wt, HKV, Q, R, a_src, a_dst, a_s, a_d, N);
    k_scan1<<<nb, 256, 0, stream>>>(cnt, rp, bsum, N);
    k_scan2<<<1, 256, 0, stream>>>(bsum, boff, nb, rp + N);
    k_scan3<<<(N + 255) / 256, 256, 0, stream>>>(rp, boff, nxt, N);
    k_fill<<<nhist, 256, 0, stream>>>(src, dst, nxt, a_s, a_d, es, E);
    k_edge<<<(N * 16 + 255) / 256, 256, 0, stream>>>(rp, es, HKV, Q, R, bias, out, N);
}

// Round 10
// 168.481 us; speedup vs baseline: 1.7817x; 1.2393x over previous
//
#include <hip/hip_runtime.h>

typedef unsigned short u16;
typedef unsigned int   u32;
typedef __attribute__((ext_vector_type(8))) short short8;
typedef __attribute__((ext_vector_type(4))) unsigned int u32x4;
typedef __attribute__((ext_vector_type(4))) float f32x4;

__device__ __forceinline__ u16 f2b(float f) {
    u32 u = __float_as_uint(f);
    u32 r = (u + 0x7fffu + ((u >> 16) & 1u)) >> 16;   // round-to-nearest-even
    return (u16)r;
}
__device__ __forceinline__ float blo(u32 w) { return __uint_as_float(w << 16); }
__device__ __forceinline__ float bhi(u32 w) { return __uint_as_float(w & 0xffff0000u); }

// ---------------- prep: Xb convert | MtB = (Wq Wk^T)/sqrt(D) | W0/Wv/Wr transpose | w0s/w0d | hist
__global__ void k_ph(const float* __restrict__ X, u16* __restrict__ Xb, int NX,
                     const float* __restrict__ Wq, const float* __restrict__ Wk, u16* __restrict__ MtB,
                     const float* __restrict__ W0, const float* __restrict__ Wv, const float* __restrict__ Wr,
                     u16* __restrict__ Wt,
                     const float* __restrict__ asrc, const float* __restrict__ adst,
                     float* __restrict__ w0s, float* __restrict__ w0d,
                     const int* __restrict__ dst, int* __restrict__ cnt, int E, int nxc) {
    int b = blockIdx.x, t = threadIdx.x;
    if (b < nxc) {
        int i0 = b * 2048 + t * 8;
        if (i0 + 8 <= NX) {
            float4 f0 = *reinterpret_cast<const float4*>(X + i0);
            float4 f1 = *reinterpret_cast<const float4*>(X + i0 + 4);
            short8 vv;
            vv[0] = (short)f2b(f0.x); vv[1] = (short)f2b(f0.y);
            vv[2] = (short)f2b(f0.z); vv[3] = (short)f2b(f0.w);
            vv[4] = (short)f2b(f1.x); vv[5] = (short)f2b(f1.y);
            vv[6] = (short)f2b(f1.z); vv[7] = (short)f2b(f1.w);
            *reinterpret_cast<short8*>(Xb + i0) = vv;
        }
    } else if (b < nxc + 64) {
        // MtB[bcol][a] = (sum_j Wq[a][j] * Wk[bcol][j]) / sqrt(128)  (B-side layout for GEMM)
        int id = (b - nxc) * 256 + t;          // [0, 16384)
        int bcol = id >> 7, a = id & 127;
        const float* wqr = Wq + a * 128;
        const float* wkr = Wk + bcol * 128;
        float dt = 0.f;
        for (int j = 0; j < 128; j += 4) {
            float4 q4 = *reinterpret_cast<const float4*>(wqr + j);
            float4 k4 = *reinterpret_cast<const float4*>(wkr + j);
            dt += q4.x * k4.x + q4.y * k4.y + q4.z * k4.z + q4.w * k4.w;
        }
        MtB[id] = f2b(dt * 0.08838834764831845f);
    } else if (b < nxc + 64 + 192) {
        // Wt[g][j][k] = W_g[k][j], g in {0:W0, 1:Wv, 2:Wr}
        int id = (b - nxc - 64) * 256 + t;     // [0, 3*16384)
        int g = id >> 14, j = (id >> 7) & 127, k = id & 127;
        const float* W = g == 0 ? W0 : g == 1 ? Wv : Wr;
        Wt[id] = f2b(W[k * 128 + j]);
    } else if (b == nxc + 256) {
        // w0s[k] = sum_j W0[k][j]*asrc[j];  w0d[k] = sum_j W0[k][j]*adst[j]
        int k = t & 127;
        const float* av = (t < 128) ? asrc : adst;
        const float* wr = W0 + k * 128;
        float dt = 0.f;
        for (int j = 0; j < 128; j += 4) {
            float4 w4 = *reinterpret_cast<const float4*>(wr + j);
            float4 a4 = *reinterpret_cast<const float4*>(av + j);
            dt += w4.x * a4.x + w4.y * a4.y + w4.z * a4.z + w4.w * a4.w;
        }
        if (t < 128) w0s[k] = dt; else w0d[k] = dt;
    } else {
        int e = (b - nxc - 257) * 256 + t;
        if (e < E) atomicAdd(&cnt[dst[e]], 1);
    }
}

// ---------------- pre-GEMM: Q' = Xb @ M (scaled); a_s/a_d = x . w0s/w0d ----------------
__global__ __launch_bounds__(512) void k_pre(const u16* __restrict__ Xb, const u16* __restrict__ MtB,
                                             const float* __restrict__ w0s, const float* __restrict__ w0d,
                                             u16* __restrict__ Qp, float* __restrict__ a_s,
                                             float* __restrict__ a_d, int N) {
    __shared__ u16 Bs[128][136];
    const int tid = threadIdx.x;
    const int row0 = blockIdx.x * 128;

    for (int c = tid; c < 128 * 16; c += 512) {
        int r = c >> 4, col8 = (c & 15) * 8;
        *reinterpret_cast<short8*>(&Bs[r][col8]) =
            *reinterpret_cast<const short8*>(MtB + r * 128 + col8);
    }

    const int wid = tid >> 6, lane = tid & 63;
    const int l15 = lane & 15;
    const int kg = (lane >> 4) * 8;
    const int arow = row0 + wid * 16 + l15;

    short8 af[4];
    if (arow < N) {
#pragma unroll
        for (int kc = 0; kc < 4; kc++)
            af[kc] = *reinterpret_cast<const short8*>(Xb + (size_t)arow * 128 + kc * 32 + kg);
    } else {
        short8 z = {0, 0, 0, 0, 0, 0, 0, 0};
#pragma unroll
        for (int kc = 0; kc < 4; kc++) af[kc] = z;
    }
    __syncthreads();

    // a_s / a_d: per-lane partial dot over its 32 k-elements, reduce across the 4 k-groups
    float ps = 0.f, pd = 0.f;
#pragma unroll
    for (int kc = 0; kc < 4; kc++) {
        float4 s0 = *reinterpret_cast<const float4*>(w0s + kc * 32 + kg);
        float4 s1 = *reinterpret_cast<const float4*>(w0s + kc * 32 + kg + 4);
        float4 d0 = *reinterpret_cast<const float4*>(w0d + kc * 32 + kg);
        float4 d1 = *reinterpret_cast<const float4*>(w0d + kc * 32 + kg + 4);
        float xv0 = blo((u32)(u16)af[kc][0] | ((u32)(u16)af[kc][1] << 16));
        // unpack 8 bf16 elements
        float x0 = blo(((u32)(u16)af[kc][0]) << 0 | 0);  // placeholder avoided below
        (void)xv0; (void)x0;
        float xs[8];
#pragma unroll
        for (int i = 0; i < 8; i++) xs[i] = __uint_as_float(((u32)(u16)af[kc][i]) << 16);
        ps += xs[0] * s0.x + xs[1] * s0.y + xs[2] * s0.z + xs[3] * s0.w
            + xs[4] * s1.x + xs[5] * s1.y + xs[6] * s1.z + xs[7] * s1.w;
        pd += xs[0] * d0.x + xs[1] * d0.y + xs[2] * d0.z + xs[3] * d0.w
            + xs[4] * d1.x + xs[5] * d1.y + xs[6] * d1.z + xs[7] * d1.w;
    }
    ps += __shfl_xor(ps, 16); ps += __shfl_xor(ps, 32);
    pd += __shfl_xor(pd, 16); pd += __shfl_xor(pd, 32);
    if (lane < 16 && arow < N) { a_s[arow] = ps; a_d[arow] = pd; }

    const int rbase = row0 + wid * 16 + ((lane >> 4) << 2);

#pragma unroll
    for (int c2 = 0; c2 < 4; c2++) {
        const int col0 = c2 * 32 + 2 * l15;
        f32x4 acc0 = {0.f, 0.f, 0.f, 0.f};
        f32x4 acc1 = {0.f, 0.f, 0.f, 0.f};
#pragma unroll
        for (int kc = 0; kc < 4; kc++) {
            short8 bf0 = *reinterpret_cast<const short8*>(&Bs[col0][kc * 32 + kg]);
            short8 bf1 = *reinterpret_cast<const short8*>(&Bs[col0 + 1][kc * 32 + kg]);
            acc0 = __builtin_amdgcn_mfma_f32_16x16x32_bf16(af[kc], bf0, acc0, 0, 0, 0);
            acc1 = __builtin_amdgcn_mfma_f32_16x16x32_bf16(af[kc], bf1, acc1, 0, 0, 0);
        }
#pragma unroll
        for (int r = 0; r < 4; r++) {
            int grow = rbase + r;
            if (grow < N) {
                u32 pk = (u32)f2b(acc0[r]) | ((u32)f2b(acc1[r]) << 16);
                *reinterpret_cast<u32*>(Qp + (size_t)grow * 128 + col0) = pk;
            }
        }
    }
}

// ---------------- CSR scan chain ----------------
__global__ __launch_bounds__(256) void k_scan1(const int* __restrict__ cnt, int* __restrict__ excl,
                                               int* __restrict__ bsum, int N) {
    __shared__ int sh[256];
    int t = threadIdx.x;
    int base = blockIdx.x * 1024 + t * 4;
    int v[4], s = 0;
#pragma unroll
    for (int j = 0; j < 4; j++) {
        int i = base + j;
        v[j] = (i < N) ? cnt[i] : 0;
        s += v[j];
    }
    sh[t] = s;
    __syncthreads();
    for (int off = 1; off < 256; off <<= 1) {
        int x = (t >= off) ? sh[t - off] : 0;
        __syncthreads();
        sh[t] += x;
        __syncthreads();
    }
    int run = sh[t] - s;
#pragma unroll
    for (int j = 0; j < 4; j++) {
        int i = base + j;
        if (i < N) excl[i] = run;
        run += v[j];
    }
    if (t == 255) bsum[blockIdx.x] = sh[255];
}

__global__ __launch_bounds__(256) void k_scan2(const int* __restrict__ bsum, int* __restrict__ boff,
                                               int nb, int* __restrict__ rp_last) {
    __shared__ int sh[256];
    int t = threadIdx.x;
    int v = (t < nb) ? bsum[t] : 0;
    sh[t] = v;
    __syncthreads();
    for (int off = 1; off < 256; off <<= 1) {
        int x = (t >= off) ? sh[t - off] : 0;
        __syncthreads();
        sh[t] += x;
        __syncthreads();
    }
    if (t < nb) boff[t] = sh[t] - v;
    if (t == 255) *rp_last = sh[255];
}

__global__ void k_scan3(int* __restrict__ rp, const int* __restrict__ boff, int* __restrict__ next, int N) {
    int i = blockIdx.x * 256 + threadIdx.x;
    if (i < N) {
        int v = rp[i] + boff[i >> 10];
        rp[i] = v;
        next[i] = v;
    }
}

// ---------------- fill: CSR scatter + precompute GAT weight per edge ----------------
__global__ void k_fill(const int* __restrict__ src, const int* __restrict__ dst, int* __restrict__ next,
                       const float* __restrict__ a_s, const float* __restrict__ a_d,
                       int2* __restrict__ es, int E) {
    int e = blockIdx.x * 256 + threadIdx.x;
    if (e < E) {
        int s = src[e], d = dst[e];
        float gl = a_s[s] + a_d[d];
        gl = gl >= 0.f ? gl : 0.2f * gl;      // LeakyReLU(0.2)
        float wg = __expf(gl);
        int p = atomicAdd(&next[d], 1);
        int2 v;
        v.x = s * 128;                        // element offset into Xb
        v.y = __float_as_int(wg);
        es[p] = v;
    }
}

// ---------------- edge phase: ONE 256B gather per edge (Xb row feeds both branches) --------
// ax[n] = (sum wg*x_s)/zg ; bx[n] = (sum wt*x_s)/zt, wt = exp(Q'_n . x_s).
// Projections deferred to k_post by linearity. No max-subtraction (validated r1-r9).
__global__ __launch_bounds__(256) void k_edge(const int* __restrict__ rp, const int2* __restrict__ es,
                                              const u16* __restrict__ Xb, const u16* __restrict__ Qp,
                                              u16* __restrict__ ax, u16* __restrict__ bx, int N) {
    const int n = (blockIdx.x * 256 + threadIdx.x) >> 4;   // one node per 16-lane group
    if (n >= N) return;
    const int l = threadIdx.x & 15;
    const int l8 = l * 8;

    u32x4 qv = *reinterpret_cast<const u32x4*>(Qp + (size_t)n * 128 + l8);
    float qf[8];
#pragma unroll
    for (int i = 0; i < 4; i++) { qf[2 * i] = blo(qv[i]); qf[2 * i + 1] = bhi(qv[i]); }

    const int beg = rp[n], end = rp[n + 1];
    const int deg = end - beg;
    const int m = deg < 16 ? deg : 16;

    int ex_l = 0;
    float ew_l = 0.f;
    if (l < m) {
        int2 el = es[beg + l];
        ex_l = el.x;
        ew_l = __int_as_float(el.y);
    }

    float axr[8] = {0.f, 0.f, 0.f, 0.f, 0.f, 0.f, 0.f, 0.f};
    float bxr[8] = {0.f, 0.f, 0.f, 0.f, 0.f, 0.f, 0.f, 0.f};
    float zg = 0.f, zt = 0.f;

    for (int j = 0; j < m; j++) {
        int ex0 = __shfl(ex_l, j, 16);
        float wg0 = __shfl(ew_l, j, 16);
        u32x4 xv = *reinterpret_cast<const u32x4*>(Xb + ex0 + l8);

        float d0 = 0.f;
#pragma unroll
        for (int i = 0; i < 4; i++) {
            d0 = fmaf(qf[2 * i], blo(xv[i]), d0);
            d0 = fmaf(qf[2 * i + 1], bhi(xv[i]), d0);
        }
        d0 += __shfl_xor(d0, 1);
        d0 += __shfl_xor(d0, 2);
        d0 += __shfl_xor(d0, 4);
        d0 += __shfl_xor(d0, 8);
        float wt0 = __expf(d0);               // scale folded into M

#pragma unroll
        for (int i = 0; i < 4; i++) {
            float x0 = blo(xv[i]), x1 = bhi(xv[i]);
            axr[2 * i]     = fmaf(wg0, x0, axr[2 * i]);
            axr[2 * i + 1] = fmaf(wg0, x1, axr[2 * i + 1]);
            bxr[2 * i]     = fmaf(wt0, x0, bxr[2 * i]);
            bxr[2 * i + 1] = fmaf(wt0, x1, bxr[2 * i + 1]);
        }
        zg += wg0;
        zt += wt0;
    }
    // rare tail: degree > 16
    for (int p = beg + 16; p < end; p++) {
        int2 e0 = es[p];
        u32x4 xv = *reinterpret_cast<const u32x4*>(Xb + e0.x + l8);
        float wg0 = __int_as_float(e0.y);
        float d0 = 0.f;
#pragma unroll
        for (int i = 0; i < 4; i++) {
            d0 = fmaf(qf[2 * i], blo(xv[i]), d0);
            d0 = fmaf(qf[2 * i + 1], bhi(xv[i]), d0);
        }
#pragma unroll
        for (int off = 1; off < 16; off <<= 1) d0 += __shfl_xor(d0, off);
        float wt0 = __expf(d0);
#pragma unroll
        for (int i = 0; i < 4; i++) {
            float x0 = blo(xv[i]), x1 = bhi(xv[i]);
            axr[2 * i]     = fmaf(wg0, x0, axr[2 * i]);
            axr[2 * i + 1] = fmaf(wg0, x1, axr[2 * i + 1]);
            bxr[2 * i]     = fmaf(wt0, x0, bxr[2 * i]);
            bxr[2 * i + 1] = fmaf(wt0, x1, bxr[2 * i + 1]);
        }
        zg += wg0;
        zt += wt0;
    }

    float ig = 1.f / (zg + 1e-16f), it = 1.f / (zt + 1e-16f);
    short8 pax, pbx;
#pragma unroll
    for (int i = 0; i < 8; i++) {
        pax[i] = (short)f2b(axr[i] * ig);
        pbx[i] = (short)f2b(bxr[i] * it);
    }
    *reinterpret_cast<short8*>(ax + (size_t)n * 128 + l8) = pax;
    *reinterpret_cast<short8*>(bx + (size_t)n * 128 + l8) = pbx;
}

// ---------------- post-GEMM: out = normalize(relu(ax@W0 + bias) + bx@Wv + x@Wr) ----------------
__device__ __forceinline__ void ld_af(const u16* __restrict__ A, int arow, int kg, int N, short8* af) {
    if (arow < N) {
#pragma unroll
        for (int kc = 0; kc < 4; kc++)
            af[kc] = *reinterpret_cast<const short8*>(A + (size_t)arow * 128 + kc * 32 + kg);
    } else {
        short8 z = {0, 0, 0, 0, 0, 0, 0, 0};
#pragma unroll
        for (int kc = 0; kc < 4; kc++) af[kc] = z;
    }
}

__global__ __launch_bounds__(512) void k_post(const u16* __restrict__ ax, const u16* __restrict__ bx,
                                              const u16* __restrict__ Xb, const u16* __restrict__ Wt,
                                              const float* __restrict__ bias, float* __restrict__ out, int N) {
    __shared__ u16 Bs[128][136];
    const int tid = threadIdx.x;
    const int row0 = blockIdx.x * 128;
    const int wid = tid >> 6, lane = tid & 63;
    const int l15 = lane & 15;
    const int kg = (lane >> 4) * 8;
    const int arow = row0 + wid * 16 + l15;
    const int rbase = row0 + wid * 16 + ((lane >> 4) << 2);

    f32x4 aG0[4], aG1[4], aD0[4], aD1[4];
#pragma unroll
    for (int c2 = 0; c2 < 4; c2++) {
        f32x4 z = {0.f, 0.f, 0.f, 0.f};
        aG0[c2] = z; aG1[c2] = z; aD0[c2] = z; aD1[c2] = z;
    }

    short8 af[4];
#pragma unroll
    for (int g = 0; g < 3; g++) {
        if (g) __syncthreads();               // prior compute done before restage
        const u16* wt = Wt + g * 16384;
        for (int c = tid; c < 128 * 16; c += 512) {
            int r = c >> 4, col8 = (c & 15) * 8;
            *reinterpret_cast<short8*>(&Bs[r][col8]) =
                *reinterpret_cast<const short8*>(wt + r * 128 + col8);
        }
        ld_af(g == 0 ? ax : g == 1 ? bx : Xb, arow, kg, N, af);
        __syncthreads();

#pragma unroll
        for (int c2 = 0; c2 < 4; c2++) {
            const int col0 = c2 * 32 + 2 * l15;
            f32x4 acc0 = (g == 0) ? aG0[c2] : aD0[c2];
            f32x4 acc1 = (g == 0) ? aG1[c2] : aD1[c2];
#pragma unroll
            for (int kc = 0; kc < 4; kc++) {
                short8 bf0 = *reinterpret_cast<const short8*>(&Bs[col0][kc * 32 + kg]);
                short8 bf1 = *reinterpret_cast<const short8*>(&Bs[col0 + 1][kc * 32 + kg]);
                acc0 = __builtin_amdgcn_mfma_f32_16x16x32_bf16(af[kc], bf0, acc0, 0, 0, 0);
                acc1 = __builtin_amdgcn_mfma_f32_16x16x32_bf16(af[kc], bf1, acc1, 0, 0, 0);
            }
            if (g == 0) { aG0[c2] = acc0; aG1[c2] = acc1; }
            else        { aD0[c2] = acc0; aD1[c2] = acc1; }
        }
    }

    // fused epilogue: relu+bias, add, row L2-normalize (row cols live across the 16 l15 lanes)
#pragma unroll
    for (int r = 0; r < 4; r++) {
        int grow = rbase + r;
        float o[8];
        float ss = 0.f;
#pragma unroll
        for (int c2 = 0; c2 < 4; c2++) {
            const int col0 = c2 * 32 + 2 * l15;
            float2 bb = *reinterpret_cast<const float2*>(bias + col0);
            float g0 = fmaxf(aG0[c2][r] + bb.x, 0.f);
            float g1 = fmaxf(aG1[c2][r] + bb.y, 0.f);
            o[2 * c2]     = g0 + aD0[c2][r];
            o[2 * c2 + 1] = g1 + aD1[c2][r];
            ss += o[2 * c2] * o[2 * c2] + o[2 * c2 + 1] * o[2 * c2 + 1];
        }
        ss += __shfl_xor(ss, 1);
        ss += __shfl_xor(ss, 2);
        ss += __shfl_xor(ss, 4);
        ss += __shfl_xor(ss, 8);
        float inv = 1.f / fmaxf(sqrtf(ss), 1e-12f);
        if (grow < N) {
#pragma unroll
            for (int c2 = 0; c2 < 4; c2++) {
                const int col0 = c2 * 32 + 2 * l15;
                float2 ov = {o[2 * c2] * inv, o[2 * c2 + 1] * inv};
                *reinterpret_cast<float2*>(out + (size_t)grow * 128 + col0) = ov;
            }
        }
    }
}

// ---------------- host launcher ----------------
extern "C" void kernel_launch(void* const* d_in, const int* in_sizes, int n_in,
                              void* d_out, int out_size, void* d_ws, size_t ws_size,
                              hipStream_t stream) {
    const int* edge = (const int*)d_in[1];
    const float* emb = (const float*)d_in[2];
    const float* gat_W = (const float*)d_in[3];
    const float* a_src = (const float*)d_in[4];
    const float* a_dst = (const float*)d_in[5];
    const float* bias = (const float*)d_in[6];
    const float* Wq = (const float*)d_in[7];
    const float* Wk = (const float*)d_in[8];
    const float* Wv = (const float*)d_in[9];
    const float* Wr = (const float*)d_in[10];

    const int E = in_sizes[1] / 2;
    const int N = in_sizes[2] / 128;
    const int* src = edge;
    const int* dst = edge + E;
    float* out = (float*)d_out;

    char* w = (char*)d_ws;
    auto alloc = [&](size_t bytes) -> char* {
        char* p = w;
        w += (bytes + 255) & ~(size_t)255;
        return p;
    };
    u16* Xb  = (u16*)alloc((size_t)N * 128 * 2);
    u16* Qp  = (u16*)alloc((size_t)N * 128 * 2);
    u16* axb = (u16*)alloc((size_t)N * 128 * 2);
    u16* bxb = (u16*)alloc((size_t)N * 128 * 2);
    u16* MtB = (u16*)alloc(128 * 128 * 2);
    u16* Wt  = (u16*)alloc(3 * 128 * 128 * 2);
    float* w0s = (float*)alloc(128 * 4);
    float* w0d = (float*)alloc(128 * 4);
    float* a_s = (float*)alloc((size_t)N * 4);
    float* a_d = (float*)alloc((size_t)N * 4);
    int* cnt  = (int*)alloc((size_t)N * 4);
    int* rp   = (int*)alloc((size_t)(N + 1) * 4);
    int* nxt  = (int*)alloc((size_t)N * 4);
    int* bsum = (int*)alloc(1024);
    int* boff = (int*)alloc(1024);
    int2* es  = (int2*)alloc((size_t)E * 8);

    const int NX = N * 128;
    const int nxc = (NX + 2047) / 2048;
    const int nb = (N + 1023) / 1024;
    const int nhist = (E + 255) / 256;

    hipMemsetAsync(cnt, 0, (size_t)N * 4, stream);
    k_ph<<<nxc + 257 + nhist, 256, 0, stream>>>(emb, Xb, NX, Wq, Wk, MtB, gat_W, Wv, Wr, Wt,
                                                a_src, a_dst, w0s, w0d, dst, cnt, E, nxc);
    k_pre<<<(N + 127) / 128, 512, 0, stream>>>(Xb, MtB, w0s, w0d, Qp, a_s, a_d, N);
    k_scan1<<<nb, 256, 0, stream>>>(cnt, rp, bsum, N);
    k_scan2<<<1, 256, 0, stream>>>(bsum, boff, nb, rp + N);
    k_scan3<<<(N + 255) / 256, 256, 0, stream>>>(rp, boff, nxt, N);
    k_fill<<<nhist, 256, 0, stream>>>(src, dst, nxt, a_s, a_d, es, E);
    k_edge<<<(N * 16 + 255) / 256, 256, 0, stream>>>(rp, es, Xb, Qp, axb, bxb, N);
    k_post<<<(N + 127) / 128, 512, 0, stream>>>(axb, bxb, Xb, Wt, bias, out, N);
}

// Round 11
// 166.824 us; speedup vs baseline: 1.7994x; 1.0099x over previous
//
#include <hip/hip_runtime.h>

typedef unsigned short u16;
typedef unsigned int   u32;
typedef __attribute__((ext_vector_type(8))) short short8;
typedef __attribute__((ext_vector_type(4))) unsigned int u32x4;
typedef __attribute__((ext_vector_type(4))) float f32x4;

__device__ __forceinline__ u16 f2b(float f) {
    u32 u = __float_as_uint(f);
    u32 r = (u + 0x7fffu + ((u >> 16) & 1u)) >> 16;   // round-to-nearest-even
    return (u16)r;
}
__device__ __forceinline__ float blo(u32 w) { return __uint_as_float(w << 16); }
__device__ __forceinline__ float bhi(u32 w) { return __uint_as_float(w & 0xffff0000u); }

// ---------------- prep: MtB = (Wq Wk^T)/sqrt(D) | W0/Wv/Wr transpose | w0s/w0d | histogram ----
// blocks [0,64): MtB; [64,256): Wt; 256: w0s/w0d; [257,...): histogram of dst
__global__ void k_prep(const float* __restrict__ Wq, const float* __restrict__ Wk, u16* __restrict__ MtB,
                       const float* __restrict__ W0, const float* __restrict__ Wv, const float* __restrict__ Wr,
                       u16* __restrict__ Wt,
                       const float* __restrict__ asrc, const float* __restrict__ adst,
                       float* __restrict__ w0s, float* __restrict__ w0d,
                       const int* __restrict__ dst, int* __restrict__ cnt, int E) {
    int b = blockIdx.x, t = threadIdx.x;
    if (b < 64) {
        // MtB[bcol][a] = (sum_j Wq[a][j] * Wk[bcol][j]) / sqrt(128)  (B-side layout for GEMM)
        int id = b * 256 + t;                  // [0, 16384)
        int bcol = id >> 7, a = id & 127;
        const float* wqr = Wq + a * 128;
        const float* wkr = Wk + bcol * 128;
        float dt = 0.f;
        for (int j = 0; j < 128; j += 4) {
            float4 q4 = *reinterpret_cast<const float4*>(wqr + j);
            float4 k4 = *reinterpret_cast<const float4*>(wkr + j);
            dt += q4.x * k4.x + q4.y * k4.y + q4.z * k4.z + q4.w * k4.w;
        }
        MtB[id] = f2b(dt * 0.08838834764831845f);
    } else if (b < 256) {
        // Wt[g][j][k] = W_g[k][j], g in {0:W0, 1:Wv, 2:Wr}
        int id = (b - 64) * 256 + t;           // [0, 3*16384)
        int g = id >> 14, j = (id >> 7) & 127, k = id & 127;
        const float* W = g == 0 ? W0 : g == 1 ? Wv : Wr;
        Wt[id] = f2b(W[k * 128 + j]);
    } else if (b == 256) {
        // w0s[k] = sum_j W0[k][j]*asrc[j];  w0d[k] = sum_j W0[k][j]*adst[j]
        int k = t & 127;
        const float* av = (t < 128) ? asrc : adst;
        const float* wr = W0 + k * 128;
        float dt = 0.f;
        for (int j = 0; j < 128; j += 4) {
            float4 w4 = *reinterpret_cast<const float4*>(wr + j);
            float4 a4 = *reinterpret_cast<const float4*>(av + j);
            dt += w4.x * a4.x + w4.y * a4.y + w4.z * a4.z + w4.w * a4.w;
        }
        if (t < 128) w0s[k] = dt; else w0d[k] = dt;
    } else {
        int e = (b - 257) * 256 + t;
        if (e < E) atomicAdd(&cnt[dst[e]], 1);
    }
}

// ---------------- pre-GEMM: reads fp32 X, emits Xb (bf16) + Q' = X@M + a_s/a_d ----------------
__global__ __launch_bounds__(512) void k_pre(const float* __restrict__ X, u16* __restrict__ Xb,
                                             const u16* __restrict__ MtB,
                                             const float* __restrict__ w0s, const float* __restrict__ w0d,
                                             u16* __restrict__ Qp, float* __restrict__ a_s,
                                             float* __restrict__ a_d, int N) {
    __shared__ u16 Bs[128][136];
    const int tid = threadIdx.x;
    const int row0 = blockIdx.x * 128;

    for (int c = tid; c < 128 * 16; c += 512) {
        int r = c >> 4, col8 = (c & 15) * 8;
        *reinterpret_cast<short8*>(&Bs[r][col8]) =
            *reinterpret_cast<const short8*>(MtB + r * 128 + col8);
    }

    const int wid = tid >> 6, lane = tid & 63;
    const int l15 = lane & 15;
    const int kg = (lane >> 4) * 8;
    const int arow = row0 + wid * 16 + l15;

    // load fp32, convert to bf16 fragments, write Xb as side effect
    short8 af[4];
    if (arow < N) {
        const float* xp = X + (size_t)arow * 128 + kg;
        u16* xbp = Xb + (size_t)arow * 128 + kg;
#pragma unroll
        for (int kc = 0; kc < 4; kc++) {
            float4 f0 = *reinterpret_cast<const float4*>(xp + kc * 32);
            float4 f1 = *reinterpret_cast<const float4*>(xp + kc * 32 + 4);
            short8 vv;
            vv[0] = (short)f2b(f0.x); vv[1] = (short)f2b(f0.y);
            vv[2] = (short)f2b(f0.z); vv[3] = (short)f2b(f0.w);
            vv[4] = (short)f2b(f1.x); vv[5] = (short)f2b(f1.y);
            vv[6] = (short)f2b(f1.z); vv[7] = (short)f2b(f1.w);
            af[kc] = vv;
            *reinterpret_cast<short8*>(xbp + kc * 32) = vv;
        }
    } else {
        short8 z = {0, 0, 0, 0, 0, 0, 0, 0};
#pragma unroll
        for (int kc = 0; kc < 4; kc++) af[kc] = z;
    }
    __syncthreads();

    // a_s / a_d: per-lane partial dot over its 32 k-elements, reduce across the 4 k-groups
    float ps = 0.f, pd = 0.f;
#pragma unroll
    for (int kc = 0; kc < 4; kc++) {
        float4 s0 = *reinterpret_cast<const float4*>(w0s + kc * 32 + kg);
        float4 s1 = *reinterpret_cast<const float4*>(w0s + kc * 32 + kg + 4);
        float4 d0 = *reinterpret_cast<const float4*>(w0d + kc * 32 + kg);
        float4 d1 = *reinterpret_cast<const float4*>(w0d + kc * 32 + kg + 4);
        float xs[8];
#pragma unroll
        for (int i = 0; i < 8; i++) xs[i] = __uint_as_float(((u32)(u16)af[kc][i]) << 16);
        ps += xs[0] * s0.x + xs[1] * s0.y + xs[2] * s0.z + xs[3] * s0.w
            + xs[4] * s1.x + xs[5] * s1.y + xs[6] * s1.z + xs[7] * s1.w;
        pd += xs[0] * d0.x + xs[1] * d0.y + xs[2] * d0.z + xs[3] * d0.w
            + xs[4] * d1.x + xs[5] * d1.y + xs[6] * d1.z + xs[7] * d1.w;
    }
    ps += __shfl_xor(ps, 16); ps += __shfl_xor(ps, 32);
    pd += __shfl_xor(pd, 16); pd += __shfl_xor(pd, 32);
    if (lane < 16 && arow < N) { a_s[arow] = ps; a_d[arow] = pd; }

    const int rbase = row0 + wid * 16 + ((lane >> 4) << 2);

#pragma unroll
    for (int c2 = 0; c2 < 4; c2++) {
        const int col0 = c2 * 32 + 2 * l15;
        f32x4 acc0 = {0.f, 0.f, 0.f, 0.f};
        f32x4 acc1 = {0.f, 0.f, 0.f, 0.f};
#pragma unroll
        for (int kc = 0; kc < 4; kc++) {
            short8 bf0 = *reinterpret_cast<const short8*>(&Bs[col0][kc * 32 + kg]);
            short8 bf1 = *reinterpret_cast<const short8*>(&Bs[col0 + 1][kc * 32 + kg]);
            acc0 = __builtin_amdgcn_mfma_f32_16x16x32_bf16(af[kc], bf0, acc0, 0, 0, 0);
            acc1 = __builtin_amdgcn_mfma_f32_16x16x32_bf16(af[kc], bf1, acc1, 0, 0, 0);
        }
#pragma unroll
        for (int r = 0; r < 4; r++) {
            int grow = rbase + r;
            if (grow < N) {
                u32 pk = (u32)f2b(acc0[r]) | ((u32)f2b(acc1[r]) << 16);
                *reinterpret_cast<u32*>(Qp + (size_t)grow * 128 + col0) = pk;
            }
        }
    }
}

// ---------------- CSR scan chain ----------------
__global__ __launch_bounds__(256) void k_scan1(const int* __restrict__ cnt, int* __restrict__ excl,
                                               int* __restrict__ bsum, int N) {
    __shared__ int sh[256];
    int t = threadIdx.x;
    int base = blockIdx.x * 1024 + t * 4;
    int v[4], s = 0;
#pragma unroll
    for (int j = 0; j < 4; j++) {
        int i = base + j;
        v[j] = (i < N) ? cnt[i] : 0;
        s += v[j];
    }
    sh[t] = s;
    __syncthreads();
    for (int off = 1; off < 256; off <<= 1) {
        int x = (t >= off) ? sh[t - off] : 0;
        __syncthreads();
        sh[t] += x;
        __syncthreads();
    }
    int run = sh[t] - s;
#pragma unroll
    for (int j = 0; j < 4; j++) {
        int i = base + j;
        if (i < N) excl[i] = run;
        run += v[j];
    }
    if (t == 255) bsum[blockIdx.x] = sh[255];
}

__global__ __launch_bounds__(256) void k_scan2(const int* __restrict__ bsum, int* __restrict__ boff,
                                               int nb, int* __restrict__ rp_last) {
    __shared__ int sh[256];
    int t = threadIdx.x;
    int v = (t < nb) ? bsum[t] : 0;
    sh[t] = v;
    __syncthreads();
    for (int off = 1; off < 256; off <<= 1) {
        int x = (t >= off) ? sh[t - off] : 0;
        __syncthreads();
        sh[t] += x;
        __syncthreads();
    }
    if (t < nb) boff[t] = sh[t] - v;
    if (t == 255) *rp_last = sh[255];
}

__global__ void k_scan3(int* __restrict__ rp, const int* __restrict__ boff, int* __restrict__ next, int N) {
    int i = blockIdx.x * 256 + threadIdx.x;
    if (i < N) {
        int v = rp[i] + boff[i >> 10];
        rp[i] = v;
        next[i] = v;
    }
}

// ---------------- fill: CSR scatter, 4B per edge (src id only) ----------------
__global__ void k_fill(const int* __restrict__ src, const int* __restrict__ dst, int* __restrict__ next,
                       int* __restrict__ cs, int E) {
    int e = blockIdx.x * 256 + threadIdx.x;
    if (e < E) {
        int p = atomicAdd(&next[dst[e]], 1);
        cs[p] = src[e];
    }
}

// ---------------- edge phase: ONE 256B gather per edge; GAT weight computed inline ----------
// Lane l of the 16-lane group preloads cs[beg+l], gathers a_s[s], computes its edge's GAT
// weight; address+weight broadcast via __shfl. No max-subtraction (validated r1-r10).
__global__ __launch_bounds__(256) void k_edge(const int* __restrict__ rp, const int* __restrict__ cs,
                                              const u16* __restrict__ Xb, const u16* __restrict__ Qp,
                                              const float* __restrict__ a_s, const float* __restrict__ a_d,
                                              u16* __restrict__ ax, u16* __restrict__ bx, int N) {
    const int n = (blockIdx.x * 256 + threadIdx.x) >> 4;   // one node per 16-lane group
    if (n >= N) return;
    const int l = threadIdx.x & 15;
    const int l8 = l * 8;

    u32x4 qv = *reinterpret_cast<const u32x4*>(Qp + (size_t)n * 128 + l8);
    float qf[8];
#pragma unroll
    for (int i = 0; i < 4; i++) { qf[2 * i] = blo(qv[i]); qf[2 * i + 1] = bhi(qv[i]); }

    const int beg = rp[n], end = rp[n + 1];
    const int deg = end - beg;
    const int m = deg < 16 ? deg : 16;
    const float adn = a_d[n];

    // lane-prefetch edge: src id, GAT weight
    int sx_l = 0;
    float wg_l = 0.f;
    if (l < m) {
        int s = cs[beg + l];
        float gl = a_s[s] + adn;
        gl = gl >= 0.f ? gl : 0.2f * gl;      // LeakyReLU(0.2)
        wg_l = __expf(gl);
        sx_l = s << 7;                        // s*128
    }

    float axr[8] = {0.f, 0.f, 0.f, 0.f, 0.f, 0.f, 0.f, 0.f};
    float bxr[8] = {0.f, 0.f, 0.f, 0.f, 0.f, 0.f, 0.f, 0.f};
    float zg = 0.f, zt = 0.f;

    for (int j = 0; j < m; j++) {
        int ex0 = __shfl(sx_l, j, 16);
        float wg0 = __shfl(wg_l, j, 16);
        u32x4 xv = *reinterpret_cast<const u32x4*>(Xb + ex0 + l8);

        float d0 = 0.f;
#pragma unroll
        for (int i = 0; i < 4; i++) {
            d0 = fmaf(qf[2 * i], blo(xv[i]), d0);
            d0 = fmaf(qf[2 * i + 1], bhi(xv[i]), d0);
        }
        d0 += __shfl_xor(d0, 1);
        d0 += __shfl_xor(d0, 2);
        d0 += __shfl_xor(d0, 4);
        d0 += __shfl_xor(d0, 8);
        float wt0 = __expf(d0);               // 1/sqrt(D) folded into M

#pragma unroll
        for (int i = 0; i < 4; i++) {
            float x0 = blo(xv[i]), x1 = bhi(xv[i]);
            axr[2 * i]     = fmaf(wg0, x0, axr[2 * i]);
            axr[2 * i + 1] = fmaf(wg0, x1, axr[2 * i + 1]);
            bxr[2 * i]     = fmaf(wt0, x0, bxr[2 * i]);
            bxr[2 * i + 1] = fmaf(wt0, x1, bxr[2 * i + 1]);
        }
        zg += wg0;
        zt += wt0;
    }
    // rare tail: degree > 16
    for (int p = beg + 16; p < end; p++) {
        int s = cs[p];
        float gl = a_s[s] + adn;
        gl = gl >= 0.f ? gl : 0.2f * gl;
        float wg0 = __expf(gl);
        u32x4 xv = *reinterpret_cast<const u32x4*>(Xb + (s << 7) + l8);
        float d0 = 0.f;
#pragma unroll
        for (int i = 0; i < 4; i++) {
            d0 = fmaf(qf[2 * i], blo(xv[i]), d0);
            d0 = fmaf(qf[2 * i + 1], bhi(xv[i]), d0);
        }
#pragma unroll
        for (int off = 1; off < 16; off <<= 1) d0 += __shfl_xor(d0, off);
        float wt0 = __expf(d0);
#pragma unroll
        for (int i = 0; i < 4; i++) {
            float x0 = blo(xv[i]), x1 = bhi(xv[i]);
            axr[2 * i]     = fmaf(wg0, x0, axr[2 * i]);
            axr[2 * i + 1] = fmaf(wg0, x1, axr[2 * i + 1]);
            bxr[2 * i]     = fmaf(wt0, x0, bxr[2 * i]);
            bxr[2 * i + 1] = fmaf(wt0, x1, bxr[2 * i + 1]);
        }
        zg += wg0;
        zt += wt0;
    }

    float ig = 1.f / (zg + 1e-16f), it = 1.f / (zt + 1e-16f);
    short8 pax, pbx;
#pragma unroll
    for (int i = 0; i < 8; i++) {
        pax[i] = (short)f2b(axr[i] * ig);
        pbx[i] = (short)f2b(bxr[i] * it);
    }
    *reinterpret_cast<short8*>(ax + (size_t)n * 128 + l8) = pax;
    *reinterpret_cast<short8*>(bx + (size_t)n * 128 + l8) = pbx;
}

// ---------------- post-GEMM: out = normalize(relu(ax@W0 + bias) + bx@Wv + x@Wr) ----------------
__device__ __forceinline__ void ld_af(const u16* __restrict__ A, int arow, int kg, int N, short8* af) {
    if (arow < N) {
#pragma unroll
        for (int kc = 0; kc < 4; kc++)
            af[kc] = *reinterpret_cast<const short8*>(A + (size_t)arow * 128 + kc * 32 + kg);
    } else {
        short8 z = {0, 0, 0, 0, 0, 0, 0, 0};
#pragma unroll
        for (int kc = 0; kc < 4; kc++) af[kc] = z;
    }
}

__global__ __launch_bounds__(512) void k_post(const u16* __restrict__ ax, const u16* __restrict__ bx,
                                              const u16* __restrict__ Xb, const u16* __restrict__ Wt,
                                              const float* __restrict__ bias, float* __restrict__ out, int N) {
    __shared__ u16 Bs[128][136];
    const int tid = threadIdx.x;
    const int row0 = blockIdx.x * 128;
    const int wid = tid >> 6, lane = tid & 63;
    const int l15 = lane & 15;
    const int kg = (lane >> 4) * 8;
    const int arow = row0 + wid * 16 + l15;
    const int rbase = row0 + wid * 16 + ((lane >> 4) << 2);

    f32x4 aG0[4], aG1[4], aD0[4], aD1[4];
#pragma unroll
    for (int c2 = 0; c2 < 4; c2++) {
        f32x4 z = {0.f, 0.f, 0.f, 0.f};
        aG0[c2] = z; aG1[c2] = z; aD0[c2] = z; aD1[c2] = z;
    }

    short8 af[4];
#pragma unroll
    for (int g = 0; g < 3; g++) {
        if (g) __syncthreads();               // prior compute done before restage
        const u16* wt = Wt + g * 16384;
        for (int c = tid; c < 128 * 16; c += 512) {
            int r = c >> 4, col8 = (c & 15) * 8;
            *reinterpret_cast<short8*>(&Bs[r][col8]) =
                *reinterpret_cast<const short8*>(wt + r * 128 + col8);
        }
        ld_af(g == 0 ? ax : g == 1 ? bx : Xb, arow, kg, N, af);
        __syncthreads();

#pragma unroll
        for (int c2 = 0; c2 < 4; c2++) {
            const int col0 = c2 * 32 + 2 * l15;
            f32x4 acc0 = (g == 0) ? aG0[c2] : aD0[c2];
            f32x4 acc1 = (g == 0) ? aG1[c2] : aD1[c2];
#pragma unroll
            for (int kc = 0; kc < 4; kc++) {
                short8 bf0 = *reinterpret_cast<const short8*>(&Bs[col0][kc * 32 + kg]);
                short8 bf1 = *reinterpret_cast<const short8*>(&Bs[col0 + 1][kc * 32 + kg]);
                acc0 = __builtin_amdgcn_mfma_f32_16x16x32_bf16(af[kc], bf0, acc0, 0, 0, 0);
                acc1 = __builtin_amdgcn_mfma_f32_16x16x32_bf16(af[kc], bf1, acc1, 0, 0, 0);
            }
            if (g == 0) { aG0[c2] = acc0; aG1[c2] = acc1; }
            else        { aD0[c2] = acc0; aD1[c2] = acc1; }
        }
    }

    // fused epilogue: relu+bias, add, row L2-normalize
#pragma unroll
    for (int r = 0; r < 4; r++) {
        int grow = rbase + r;
        float o[8];
        float ss = 0.f;
#pragma unroll
        for (int c2 = 0; c2 < 4; c2++) {
            const int col0 = c2 * 32 + 2 * l15;
            float2 bb = *reinterpret_cast<const float2*>(bias + col0);
            float g0 = fmaxf(aG0[c2][r] + bb.x, 0.f);
            float g1 = fmaxf(aG1[c2][r] + bb.y, 0.f);
            o[2 * c2]     = g0 + aD0[c2][r];
            o[2 * c2 + 1] = g1 + aD1[c2][r];
            ss += o[2 * c2] * o[2 * c2] + o[2 * c2 + 1] * o[2 * c2 + 1];
        }
        ss += __shfl_xor(ss, 1);
        ss += __shfl_xor(ss, 2);
        ss += __shfl_xor(ss, 4);
        ss += __shfl_xor(ss, 8);
        float inv = 1.f / fmaxf(sqrtf(ss), 1e-12f);
        if (grow < N) {
#pragma unroll
            for (int c2 = 0; c2 < 4; c2++) {
                const int col0 = c2 * 32 + 2 * l15;
                float2 ov = {o[2 * c2] * inv, o[2 * c2 + 1] * inv};
                *reinterpret_cast<float2*>(out + (size_t)grow * 128 + col0) = ov;
            }
        }
    }
}

// ---------------- host launcher ----------------
extern "C" void kernel_launch(void* const* d_in, const int* in_sizes, int n_in,
                              void* d_out, int out_size, void* d_ws, size_t ws_size,
                              hipStream_t stream) {
    const int* edge = (const int*)d_in[1];
    const float* emb = (const float*)d_in[2];
    const float* gat_W = (const float*)d_in[3];
    const float* a_src = (const float*)d_in[4];
    const float* a_dst = (const float*)d_in[5];
    const float* bias = (const float*)d_in[6];
    const float* Wq = (const float*)d_in[7];
    const float* Wk = (const float*)d_in[8];
    const float* Wv = (const float*)d_in[9];
    const float* Wr = (const float*)d_in[10];

    const int E = in_sizes[1] / 2;
    const int N = in_sizes[2] / 128;
    const int* src = edge;
    const int* dst = edge + E;
    float* out = (float*)d_out;

    char* w = (char*)d_ws;
    auto alloc = [&](size_t bytes) -> char* {
        char* p = w;
        w += (bytes + 255) & ~(size_t)255;
        return p;
    };
    u16* Xb  = (u16*)alloc((size_t)N * 128 * 2);
    u16* Qp  = (u16*)alloc((size_t)N * 128 * 2);
    u16* axb = (u16*)alloc((size_t)N * 128 * 2);
    u16* bxb = (u16*)alloc((size_t)N * 128 * 2);
    u16* MtB = (u16*)alloc(128 * 128 * 2);
    u16* Wt  = (u16*)alloc(3 * 128 * 128 * 2);
    float* w0s = (float*)alloc(128 * 4);
    float* w0d = (float*)alloc(128 * 4);
    float* a_s = (float*)alloc((size_t)N * 4);
    float* a_d = (float*)alloc((size_t)N * 4);
    int* cnt  = (int*)alloc((size_t)N * 4);
    int* rp   = (int*)alloc((size_t)(N + 1) * 4);
    int* nxt  = (int*)alloc((size_t)N * 4);
    int* bsum = (int*)alloc(1024);
    int* boff = (int*)alloc(1024);
    int* cs   = (int*)alloc((size_t)E * 4);

    const int nb = (N + 1023) / 1024;
    const int nhist = (E + 255) / 256;

    hipMemsetAsync(cnt, 0, (size_t)N * 4, stream);
    k_prep<<<257 + nhist, 256, 0, stream>>>(Wq, Wk, MtB, gat_W, Wv, Wr, Wt,
                                            a_src, a_dst, w0s, w0d, dst, cnt, E);
    k_pre<<<(N + 127) / 128, 512, 0, stream>>>(emb, Xb, MtB, w0s, w0d, Qp, a_s, a_d, N);
    k_scan1<<<nb, 256, 0, stream>>>(cnt, rp, bsum, N);
    k_scan2<<<1, 256, 0, stream>>>(bsum, boff, nb, rp + N);
    k_scan3<<<(N + 255) / 256, 256, 0, stream>>>(rp, boff, nxt, N);
    k_fill<<<nhist, 256, 0, stream>>>(src, dst, nxt, cs, E);
    k_edge<<<(N * 16 + 255) / 256, 256, 0, stream>>>(rp, cs, Xb, Qp, a_s, a_d, axb, bxb, N);
    k_post<<<(N + 127) / 128, 512, 0, stream>>>(axb, bxb, Xb, Wt, bias, out, N);
}

// Round 12
// 160.409 us; speedup vs baseline: 1.8713x; 1.0400x over previous
//
#include <hip/hip_runtime.h>

typedef unsigned short u16;
typedef unsigned int   u32;
typedef __attribute__((ext_vector_type(8))) short short8;
typedef __attribute__((ext_vector_type(4))) unsigned int u32x4;
typedef __attribute__((ext_vector_type(4))) float f32x4;

__device__ __forceinline__ u16 f2b(float f) {
    u32 u = __float_as_uint(f);
    u32 r = (u + 0x7fffu + ((u >> 16) & 1u)) >> 16;   // round-to-nearest-even
    return (u16)r;
}
__device__ __forceinline__ float blo(u32 w) { return __uint_as_float(w << 16); }
__device__ __forceinline__ float bhi(u32 w) { return __uint_as_float(w & 0xffff0000u); }

// ---------------- prep: MtB | Wf (fragment-ordered W0/Wv/Wr) | w0s/w0d | histogram ----------
// blocks [0,64): MtB; [64,256): Wf; 256: w0s/w0d; [257,...): histogram of dst
__global__ void k_prep(const float* __restrict__ Wq, const float* __restrict__ Wk, u16* __restrict__ MtB,
                       const float* __restrict__ W0, const float* __restrict__ Wv, const float* __restrict__ Wr,
                       u16* __restrict__ Wf,
                       const float* __restrict__ asrc, const float* __restrict__ adst,
                       float* __restrict__ w0s, float* __restrict__ w0d,
                       const int* __restrict__ dst, int* __restrict__ cnt, int E) {
    int b = blockIdx.x, t = threadIdx.x;
    if (b < 64) {
        // MtB[bcol][a] = (sum_j Wq[a][j] * Wk[bcol][j]) / sqrt(128)  (B-side layout for GEMM)
        int id = b * 256 + t;                  // [0, 16384)
        int bcol = id >> 7, a = id & 127;
        const float* wqr = Wq + a * 128;
        const float* wkr = Wk + bcol * 128;
        float dt = 0.f;
        for (int j = 0; j < 128; j += 4) {
            float4 q4 = *reinterpret_cast<const float4*>(wqr + j);
            float4 k4 = *reinterpret_cast<const float4*>(wkr + j);
            dt += q4.x * k4.x + q4.y * k4.y + q4.z * k4.z + q4.w * k4.w;
        }
        MtB[id] = f2b(dt * 0.08838834764831845f);
    } else if (b < 256) {
        // Wf fragment order: chunk = ((g*4+w)*2+p)*4+kc ; within chunk lane l elems i:
        //   col = w*32 + 2*(l&15) + p ; k = kc*32 + (l>>4)*8 + i ; value = W_g[k][col]
        int id = (b - 64) * 256 + t;           // [0, 49152)
        int i = id & 7, l = (id >> 3) & 63, chunk = id >> 9;
        int kc = chunk & 3, p = (chunk >> 2) & 1, wv = (chunk >> 3) & 3, g = chunk >> 5;
        int col = wv * 32 + 2 * (l & 15) + p;
        int k = kc * 32 + (l >> 4) * 8 + i;
        const float* W = g == 0 ? W0 : g == 1 ? Wv : Wr;
        Wf[id] = f2b(W[k * 128 + col]);
    } else if (b == 256) {
        // w0s[k] = sum_j W0[k][j]*asrc[j];  w0d[k] = sum_j W0[k][j]*adst[j]
        int k = t & 127;
        const float* av = (t < 128) ? asrc : adst;
        const float* wr = W0 + k * 128;
        float dt = 0.f;
        for (int j = 0; j < 128; j += 4) {
            float4 w4 = *reinterpret_cast<const float4*>(wr + j);
            float4 a4 = *reinterpret_cast<const float4*>(av + j);
            dt += w4.x * a4.x + w4.y * a4.y + w4.z * a4.z + w4.w * a4.w;
        }
        if (t < 128) w0s[k] = dt; else w0d[k] = dt;
    } else {
        int e = (b - 257) * 256 + t;
        if (e < E) atomicAdd(&cnt[dst[e]], 1);
    }
}

// ---------------- pre-GEMM: reads fp32 X, emits Xb (bf16) + Q' = X@M + a_s/a_d ----------------
__global__ __launch_bounds__(512) void k_pre(const float* __restrict__ X, u16* __restrict__ Xb,
                                             const u16* __restrict__ MtB,
                                             const float* __restrict__ w0s, const float* __restrict__ w0d,
                                             u16* __restrict__ Qp, float* __restrict__ a_s,
                                             float* __restrict__ a_d, int N) {
    __shared__ u16 Bs[128][136];
    const int tid = threadIdx.x;
    const int row0 = blockIdx.x * 128;

    for (int c = tid; c < 128 * 16; c += 512) {
        int r = c >> 4, col8 = (c & 15) * 8;
        *reinterpret_cast<short8*>(&Bs[r][col8]) =
            *reinterpret_cast<const short8*>(MtB + r * 128 + col8);
    }

    const int wid = tid >> 6, lane = tid & 63;
    const int l15 = lane & 15;
    const int kg = (lane >> 4) * 8;
    const int arow = row0 + wid * 16 + l15;

    short8 af[4];
    if (arow < N) {
        const float* xp = X + (size_t)arow * 128 + kg;
        u16* xbp = Xb + (size_t)arow * 128 + kg;
#pragma unroll
        for (int kc = 0; kc < 4; kc++) {
            float4 f0 = *reinterpret_cast<const float4*>(xp + kc * 32);
            float4 f1 = *reinterpret_cast<const float4*>(xp + kc * 32 + 4);
            short8 vv;
            vv[0] = (short)f2b(f0.x); vv[1] = (short)f2b(f0.y);
            vv[2] = (short)f2b(f0.z); vv[3] = (short)f2b(f0.w);
            vv[4] = (short)f2b(f1.x); vv[5] = (short)f2b(f1.y);
            vv[6] = (short)f2b(f1.z); vv[7] = (short)f2b(f1.w);
            af[kc] = vv;
            *reinterpret_cast<short8*>(xbp + kc * 32) = vv;
        }
    } else {
        short8 z = {0, 0, 0, 0, 0, 0, 0, 0};
#pragma unroll
        for (int kc = 0; kc < 4; kc++) af[kc] = z;
    }
    __syncthreads();

    float ps = 0.f, pd = 0.f;
#pragma unroll
    for (int kc = 0; kc < 4; kc++) {
        float4 s0 = *reinterpret_cast<const float4*>(w0s + kc * 32 + kg);
        float4 s1 = *reinterpret_cast<const float4*>(w0s + kc * 32 + kg + 4);
        float4 d0 = *reinterpret_cast<const float4*>(w0d + kc * 32 + kg);
        float4 d1 = *reinterpret_cast<const float4*>(w0d + kc * 32 + kg + 4);
        float xs[8];
#pragma unroll
        for (int i = 0; i < 8; i++) xs[i] = __uint_as_float(((u32)(u16)af[kc][i]) << 16);
        ps += xs[0] * s0.x + xs[1] * s0.y + xs[2] * s0.z + xs[3] * s0.w
            + xs[4] * s1.x + xs[5] * s1.y + xs[6] * s1.z + xs[7] * s1.w;
        pd += xs[0] * d0.x + xs[1] * d0.y + xs[2] * d0.z + xs[3] * d0.w
            + xs[4] * d1.x + xs[5] * d1.y + xs[6] * d1.z + xs[7] * d1.w;
    }
    ps += __shfl_xor(ps, 16); ps += __shfl_xor(ps, 32);
    pd += __shfl_xor(pd, 16); pd += __shfl_xor(pd, 32);
    if (lane < 16 && arow < N) { a_s[arow] = ps; a_d[arow] = pd; }

    const int rbase = row0 + wid * 16 + ((lane >> 4) << 2);

#pragma unroll
    for (int c2 = 0; c2 < 4; c2++) {
        const int col0 = c2 * 32 + 2 * l15;
        f32x4 acc0 = {0.f, 0.f, 0.f, 0.f};
        f32x4 acc1 = {0.f, 0.f, 0.f, 0.f};
#pragma unroll
        for (int kc = 0; kc < 4; kc++) {
            short8 bf0 = *reinterpret_cast<const short8*>(&Bs[col0][kc * 32 + kg]);
            short8 bf1 = *reinterpret_cast<const short8*>(&Bs[col0 + 1][kc * 32 + kg]);
            acc0 = __builtin_amdgcn_mfma_f32_16x16x32_bf16(af[kc], bf0, acc0, 0, 0, 0);
            acc1 = __builtin_amdgcn_mfma_f32_16x16x32_bf16(af[kc], bf1, acc1, 0, 0, 0);
        }
#pragma unroll
        for (int r = 0; r < 4; r++) {
            int grow = rbase + r;
            if (grow < N) {
                u32 pk = (u32)f2b(acc0[r]) | ((u32)f2b(acc1[r]) << 16);
                *reinterpret_cast<u32*>(Qp + (size_t)grow * 128 + col0) = pk;
            }
        }
    }
}

// ---------------- CSR scan chain ----------------
__global__ __launch_bounds__(256) void k_scan1(const int* __restrict__ cnt, int* __restrict__ excl,
                                               int* __restrict__ bsum, int N) {
    __shared__ int sh[256];
    int t = threadIdx.x;
    int base = blockIdx.x * 1024 + t * 4;
    int v[4], s = 0;
#pragma unroll
    for (int j = 0; j < 4; j++) {
        int i = base + j;
        v[j] = (i < N) ? cnt[i] : 0;
        s += v[j];
    }
    sh[t] = s;
    __syncthreads();
    for (int off = 1; off < 256; off <<= 1) {
        int x = (t >= off) ? sh[t - off] : 0;
        __syncthreads();
        sh[t] += x;
        __syncthreads();
    }
    int run = sh[t] - s;
#pragma unroll
    for (int j = 0; j < 4; j++) {
        int i = base + j;
        if (i < N) excl[i] = run;
        run += v[j];
    }
    if (t == 255) bsum[blockIdx.x] = sh[255];
}

__global__ __launch_bounds__(256) void k_scan2(const int* __restrict__ bsum, int* __restrict__ boff,
                                               int nb, int* __restrict__ rp_last) {
    __shared__ int sh[256];
    int t = threadIdx.x;
    int v = (t < nb) ? bsum[t] : 0;
    sh[t] = v;
    __syncthreads();
    for (int off = 1; off < 256; off <<= 1) {
        int x = (t >= off) ? sh[t - off] : 0;
        __syncthreads();
        sh[t] += x;
        __syncthreads();
    }
    if (t < nb) boff[t] = sh[t] - v;
    if (t == 255) *rp_last = sh[255];
}

__global__ void k_scan3(int* __restrict__ rp, const int* __restrict__ boff, int* __restrict__ next, int N) {
    int i = blockIdx.x * 256 + threadIdx.x;
    if (i < N) {
        int v = rp[i] + boff[i >> 10];
        rp[i] = v;
        next[i] = v;
    }
}

// ---------------- fill: CSR scatter, 4B per edge (src id only) ----------------
__global__ void k_fill(const int* __restrict__ src, const int* __restrict__ dst, int* __restrict__ next,
                       int* __restrict__ cs, int E) {
    int e = blockIdx.x * 256 + threadIdx.x;
    if (e < E) {
        int p = atomicAdd(&next[dst[e]], 1);
        cs[p] = src[e];
    }
}

// ---------------- fused edge + post: gather/softmax -> LDS A-tiles -> MFMA -> out ----------
// Phase A: 16-lane group per node (16 nodes/block), one 256B Xb gather per edge, both
// softmax branches; ax/bx rows land in LDS (bf16, same quantization as the old global
// round-trip). Phase B: 4 waves x 32 cols, B-fragments streamed from fragment-ordered Wf
// (1KB contiguous per wave-load, L2-broadcast), D = bx@Wv + x@Wr chained in one acc;
// cross-wave row-norm via small LDS reduce. No max-subtraction (validated r1-r11).
__global__ __launch_bounds__(256) void k_edge(const int* __restrict__ rp, const int* __restrict__ cs,
                                              const u16* __restrict__ Xb, const u16* __restrict__ Qp,
                                              const float* __restrict__ a_s, const float* __restrict__ a_d,
                                              const u16* __restrict__ Wf, const float* __restrict__ bias,
                                              float* __restrict__ out, int N) {
    __shared__ u16 As[3][16][136];   // [ax|bx|x][node][col] (+8 pad)
    __shared__ float ssp[4][16];     // per-wave row-norm partials
    const int tid = threadIdx.x;
    const int node0 = blockIdx.x * 16;
    const int g16 = tid >> 4;        // group / node index within block
    const int n = node0 + g16;
    const int l = tid & 15;
    const int l8 = l * 8;

    // ---------------- phase A ----------------
    if (n < N) {
        u32x4 qv = *reinterpret_cast<const u32x4*>(Qp + (size_t)n * 128 + l8);
        float qf[8];
#pragma unroll
        for (int i = 0; i < 4; i++) { qf[2 * i] = blo(qv[i]); qf[2 * i + 1] = bhi(qv[i]); }

        const int beg = rp[n], end = rp[n + 1];
        const int deg = end - beg;
        const int m = deg < 16 ? deg : 16;
        const float adn = a_d[n];

        int sx_l = 0;
        float wg_l = 0.f;
        if (l < m) {
            int s = cs[beg + l];
            float gl = a_s[s] + adn;
            gl = gl >= 0.f ? gl : 0.2f * gl;  // LeakyReLU(0.2)
            wg_l = __expf(gl);
            sx_l = s << 7;
        }

        float axr[8] = {0.f, 0.f, 0.f, 0.f, 0.f, 0.f, 0.f, 0.f};
        float bxr[8] = {0.f, 0.f, 0.f, 0.f, 0.f, 0.f, 0.f, 0.f};
        float zg = 0.f, zt = 0.f;

        for (int j = 0; j < m; j++) {
            int ex0 = __shfl(sx_l, j, 16);
            float wg0 = __shfl(wg_l, j, 16);
            u32x4 xv = *reinterpret_cast<const u32x4*>(Xb + ex0 + l8);

            float d0 = 0.f;
#pragma unroll
            for (int i = 0; i < 4; i++) {
                d0 = fmaf(qf[2 * i], blo(xv[i]), d0);
                d0 = fmaf(qf[2 * i + 1], bhi(xv[i]), d0);
            }
            d0 += __shfl_xor(d0, 1);
            d0 += __shfl_xor(d0, 2);
            d0 += __shfl_xor(d0, 4);
            d0 += __shfl_xor(d0, 8);
            float wt0 = __expf(d0);           // 1/sqrt(D) folded into M

#pragma unroll
            for (int i = 0; i < 4; i++) {
                float x0 = blo(xv[i]), x1 = bhi(xv[i]);
                axr[2 * i]     = fmaf(wg0, x0, axr[2 * i]);
                axr[2 * i + 1] = fmaf(wg0, x1, axr[2 * i + 1]);
                bxr[2 * i]     = fmaf(wt0, x0, bxr[2 * i]);
                bxr[2 * i + 1] = fmaf(wt0, x1, bxr[2 * i + 1]);
            }
            zg += wg0;
            zt += wt0;
        }
        for (int p = beg + 16; p < end; p++) {
            int s = cs[p];
            float gl = a_s[s] + adn;
            gl = gl >= 0.f ? gl : 0.2f * gl;
            float wg0 = __expf(gl);
            u32x4 xv = *reinterpret_cast<const u32x4*>(Xb + (s << 7) + l8);
            float d0 = 0.f;
#pragma unroll
            for (int i = 0; i < 4; i++) {
                d0 = fmaf(qf[2 * i], blo(xv[i]), d0);
                d0 = fmaf(qf[2 * i + 1], bhi(xv[i]), d0);
            }
#pragma unroll
            for (int off = 1; off < 16; off <<= 1) d0 += __shfl_xor(d0, off);
            float wt0 = __expf(d0);
#pragma unroll
            for (int i = 0; i < 4; i++) {
                float x0 = blo(xv[i]), x1 = bhi(xv[i]);
                axr[2 * i]     = fmaf(wg0, x0, axr[2 * i]);
                axr[2 * i + 1] = fmaf(wg0, x1, axr[2 * i + 1]);
                bxr[2 * i]     = fmaf(wt0, x0, bxr[2 * i]);
                bxr[2 * i + 1] = fmaf(wt0, x1, bxr[2 * i + 1]);
            }
            zg += wg0;
            zt += wt0;
        }

        float ig = 1.f / (zg + 1e-16f), it = 1.f / (zt + 1e-16f);
        short8 pax, pbx;
#pragma unroll
        for (int i = 0; i < 8; i++) {
            pax[i] = (short)f2b(axr[i] * ig);
            pbx[i] = (short)f2b(bxr[i] * it);
        }
        *reinterpret_cast<short8*>(&As[0][g16][l8]) = pax;
        *reinterpret_cast<short8*>(&As[1][g16][l8]) = pbx;
        *reinterpret_cast<short8*>(&As[2][g16][l8]) =
            *reinterpret_cast<const short8*>(Xb + ((size_t)n << 7) + l8);
    } else {
        short8 z = {0, 0, 0, 0, 0, 0, 0, 0};
        *reinterpret_cast<short8*>(&As[0][g16][l8]) = z;
        *reinterpret_cast<short8*>(&As[1][g16][l8]) = z;
        *reinterpret_cast<short8*>(&As[2][g16][l8]) = z;
    }
    __syncthreads();

    // ---------------- phase B ----------------
    const int w = tid >> 6;          // wave id: cols [w*32, w*32+32)
    const int lane = tid & 63;
    const int l15 = lane & 15;
    const int q = lane >> 4;
    const int kg = q * 8;

    f32x4 aG0 = {0.f, 0.f, 0.f, 0.f}, aG1 = {0.f, 0.f, 0.f, 0.f};
    f32x4 aD0 = {0.f, 0.f, 0.f, 0.f}, aD1 = {0.f, 0.f, 0.f, 0.f};

#pragma unroll
    for (int g = 0; g < 3; g++) {
        short8 af[4];
#pragma unroll
        for (int kc = 0; kc < 4; kc++)
            af[kc] = *reinterpret_cast<const short8*>(&As[g][l15][kc * 32 + kg]);
        const u16* wfg = Wf + (((g * 4 + w) * 2) << 11);   // chunk ((g*4+w)*2+0)*4, *512 u16
#pragma unroll
        for (int kc = 0; kc < 4; kc++) {
            short8 bf0 = *reinterpret_cast<const short8*>(wfg + kc * 512 + lane * 8);
            short8 bf1 = *reinterpret_cast<const short8*>(wfg + (4 + kc) * 512 + lane * 8);
            if (g == 0) {
                aG0 = __builtin_amdgcn_mfma_f32_16x16x32_bf16(af[kc], bf0, aG0, 0, 0, 0);
                aG1 = __builtin_amdgcn_mfma_f32_16x16x32_bf16(af[kc], bf1, aG1, 0, 0, 0);
            } else {
                aD0 = __builtin_amdgcn_mfma_f32_16x16x32_bf16(af[kc], bf0, aD0, 0, 0, 0);
                aD1 = __builtin_amdgcn_mfma_f32_16x16x32_bf16(af[kc], bf1, aD1, 0, 0, 0);
            }
        }
    }

    // epilogue: relu+bias, add, cross-wave row L2-norm, store
    const int col0 = w * 32 + 2 * l15;
    float2 bb = *reinterpret_cast<const float2*>(bias + col0);
    float o0[4], o1[4], ssr[4];
#pragma unroll
    for (int r = 0; r < 4; r++) {
        float g0 = fmaxf(aG0[r] + bb.x, 0.f);
        float g1 = fmaxf(aG1[r] + bb.y, 0.f);
        o0[r] = g0 + aD0[r];
        o1[r] = g1 + aD1[r];
        ssr[r] = o0[r] * o0[r] + o1[r] * o1[r];
    }
#pragma unroll
    for (int off = 1; off < 16; off <<= 1) {
#pragma unroll
        for (int r = 0; r < 4; r++) ssr[r] += __shfl_xor(ssr[r], off);
    }
    if (l15 == 0) {
#pragma unroll
        for (int r = 0; r < 4; r++) ssp[w][q * 4 + r] = ssr[r];
    }
    __syncthreads();
#pragma unroll
    for (int r = 0; r < 4; r++) {
        int row = q * 4 + r;
        float tot = ssp[0][row] + ssp[1][row] + ssp[2][row] + ssp[3][row];
        float inv = 1.f / fmaxf(sqrtf(tot), 1e-12f);
        int grow = node0 + row;
        if (grow < N) {
            float2 ov = {o0[r] * inv, o1[r] * inv};
            *reinterpret_cast<float2*>(out + (size_t)grow * 128 + col0) = ov;
        }
    }
}

// ---------------- host launcher ----------------
extern "C" void kernel_launch(void* const* d_in, const int* in_sizes, int n_in,
                              void* d_out, int out_size, void* d_ws, size_t ws_size,
                              hipStream_t stream) {
    const int* edge = (const int*)d_in[1];
    const float* emb = (const float*)d_in[2];
    const float* gat_W = (const float*)d_in[3];
    const float* a_src = (const float*)d_in[4];
    const float* a_dst = (const float*)d_in[5];
    const float* bias = (const float*)d_in[6];
    const float* Wq = (const float*)d_in[7];
    const float* Wk = (const float*)d_in[8];
    const float* Wv = (const float*)d_in[9];
    const float* Wr = (const float*)d_in[10];

    const int E = in_sizes[1] / 2;
    const int N = in_sizes[2] / 128;
    const int* src = edge;
    const int* dst = edge + E;
    float* out = (float*)d_out;

    char* w = (char*)d_ws;
    auto alloc = [&](size_t bytes) -> char* {
        char* p = w;
        w += (bytes + 255) & ~(size_t)255;
        return p;
    };
    u16* Xb  = (u16*)alloc((size_t)N * 128 * 2);
    u16* Qp  = (u16*)alloc((size_t)N * 128 * 2);
    u16* MtB = (u16*)alloc(128 * 128 * 2);
    u16* Wf  = (u16*)alloc(3 * 128 * 128 * 2);
    float* w0s = (float*)alloc(128 * 4);
    float* w0d = (float*)alloc(128 * 4);
    float* a_s = (float*)alloc((size_t)N * 4);
    float* a_d = (float*)alloc((size_t)N * 4);
    int* cnt  = (int*)alloc((size_t)N * 4);
    int* rp   = (int*)alloc((size_t)(N + 1) * 4);
    int* nxt  = (int*)alloc((size_t)N * 4);
    int* bsum = (int*)alloc(1024);
    int* boff = (int*)alloc(1024);
    int* cs   = (int*)alloc((size_t)E * 4);

    const int nb = (N + 1023) / 1024;
    const int nhist = (E + 255) / 256;

    hipMemsetAsync(cnt, 0, (size_t)N * 4, stream);
    k_prep<<<257 + nhist, 256, 0, stream>>>(Wq, Wk, MtB, gat_W, Wv, Wr, Wf,
                                            a_src, a_dst, w0s, w0d, dst, cnt, E);
    k_pre<<<(N + 127) / 128, 512, 0, stream>>>(emb, Xb, MtB, w0s, w0d, Qp, a_s, a_d, N);
    k_scan1<<<nb, 256, 0, stream>>>(cnt, rp, bsum, N);
    k_scan2<<<1, 256, 0, stream>>>(bsum, boff, nb, rp + N);
    k_scan3<<<(N + 255) / 256, 256, 0, stream>>>(rp, boff, nxt, N);
    k_fill<<<nhist, 256, 0, stream>>>(src, dst, nxt, cs, E);
    k_edge<<<(N + 15) / 16, 256, 0, stream>>>(rp, cs, Xb, Qp, a_s, a_d, Wf, bias, out, N);
}